// Round 3
// baseline (166.332 us; speedup 1.0000x reference)
//
#include <hip/hip_runtime.h>
#include <math.h>

#define EPS_BN 1e-5f

// ---------------------------------------------------------------------------
// Kernel 1: transpose fc1_w (64,784) -> wt (784,64)
// ---------------------------------------------------------------------------
__global__ __launch_bounds__(256) void k_transpose(const float* __restrict__ w,
                                                   float* __restrict__ wt) {
    int t = blockIdx.x * 256 + threadIdx.x;
    if (t < 784 * 64) {
        int k = t >> 6;
        int o = t & 63;
        wt[t] = w[o * 784 + k];
    }
}

// ---------------------------------------------------------------------------
// Kernel 2: conv1+pool, conv2+pool, heads, flat write — 2 img/block, 256 thr
// ---------------------------------------------------------------------------
__global__ __launch_bounds__(256, 8) void k_conv(
    const float* __restrict__ x,
    const float* __restrict__ c1w, const float* __restrict__ c1b,
    const float* __restrict__ c2w, const float* __restrict__ c2b,
    const float* __restrict__ sw1, const float* __restrict__ sb1,
    const float* __restrict__ sw2, const float* __restrict__ sb2,
    const float* __restrict__ ew1, const float* __restrict__ eb1,
    const float* __restrict__ ew2, const float* __restrict__ eb2,
    const float* __restrict__ ew3, const float* __restrict__ eb3,
    const float* __restrict__ mem,
    float* __restrict__ flat_out, float* __restrict__ out, int bsz)
{
    __shared__ float sxs2[2][812];     // input (pitch 29); later flat row (784)
    __shared__ float s1[2][8][210];    // pooled conv1: 14 rows x pitch 15

    const int tid  = threadIdx.x;
    const int img0 = blockIdx.x * 2;

    // ---- stage 2 input images (padded pitch 29)
    const float* xb = x + (size_t)img0 * 784;
    for (int i = tid; i < 2 * 784; i += 256) {
        int im = i / 784;
        int j  = i - im * 784;
        sxs2[im][(j / 28) * 29 + (j % 28)] = xb[i];
    }
    __syncthreads();

    // ---- conv1 (1->8) + relu + pool: 196 tasks, each = (img, py, px-pair)
    if (tid < 196) {
        int im  = tid / 98;
        int r   = tid - im * 98;
        int py  = r / 7;
        int pxq = r - py * 7;          // px pair: px0 = 2*pxq, px0+1
        int br  = 2 * py - 1;
        int bc  = 4 * pxq - 1;
        const float* sp = &sxs2[im][0];
        float win[4][6];
        #pragma unroll
        for (int wy = 0; wy < 4; ++wy) {
            int iy = br + wy;
            bool oy = (unsigned)iy < 28u;
            #pragma unroll
            for (int wx = 0; wx < 6; ++wx) {
                int ix = bc + wx;
                win[wy][wx] = (oy && (unsigned)ix < 28u) ? sp[iy * 29 + ix] : 0.f;
            }
        }
        #pragma unroll
        for (int c = 0; c < 8; ++c) {
            const float* wp = &c1w[c * 9];            // uniform -> s_load
            float bb = c1b[c];
            float a[2][2][2];                          // [q][dy][dx]
            #pragma unroll
            for (int q = 0; q < 2; ++q)
                #pragma unroll
                for (int dy = 0; dy < 2; ++dy)
                    #pragma unroll
                    for (int dx = 0; dx < 2; ++dx) a[q][dy][dx] = bb;
            #pragma unroll
            for (int ky = 0; ky < 3; ++ky) {
                #pragma unroll
                for (int kx = 0; kx < 3; ++kx) {
                    float wv = wp[ky * 3 + kx];
                    #pragma unroll
                    for (int q = 0; q < 2; ++q)
                        #pragma unroll
                        for (int dy = 0; dy < 2; ++dy)
                            #pragma unroll
                            for (int dx = 0; dx < 2; ++dx)
                                a[q][dy][dx] += win[dy + ky][2 * q + dx + kx] * wv;
                }
            }
            #pragma unroll
            for (int q = 0; q < 2; ++q) {
                float m = fmaxf(fmaxf(a[q][0][0], a[q][0][1]),
                                fmaxf(a[q][1][0], a[q][1][1]));
                s1[im][c][py * 15 + 2 * pxq + q] = fmaxf(m, 0.f);
            }
        }
    }
    __syncthreads();

    // ---- conv2 (8->16) + relu + pool: wave=(img,cgroup of 8), lane=position
    {
        const int im = __builtin_amdgcn_readfirstlane(tid >> 7);
        const int cg = __builtin_amdgcn_readfirstlane((tid >> 6) & 1);
        const int p  = tid & 63;
        if (p < 49) {
            int py = p / 7, px = p - py * 7;
            int br = 2 * py - 1, bc = 2 * px - 1;
            float acc[8][4];
            #pragma unroll
            for (int c = 0; c < 8; ++c) {
                float bb = c2b[cg * 8 + c];
                acc[c][0] = bb; acc[c][1] = bb; acc[c][2] = bb; acc[c][3] = bb;
            }
            for (int ic = 0; ic < 8; ++ic) {
                const float* sp = &s1[im][ic][0];
                float win[4][4];
                #pragma unroll
                for (int wy = 0; wy < 4; ++wy) {
                    int iy = br + wy;
                    bool oy = (unsigned)iy < 14u;
                    #pragma unroll
                    for (int wx = 0; wx < 4; ++wx) {
                        int ix = bc + wx;
                        win[wy][wx] = (oy && (unsigned)ix < 14u) ? sp[iy * 15 + ix] : 0.f;
                    }
                }
                #pragma unroll
                for (int c = 0; c < 8; ++c) {
                    const float* wp = &c2w[((cg * 8 + c) * 8 + ic) * 9];  // s_load
                    #pragma unroll
                    for (int ky = 0; ky < 3; ++ky) {
                        #pragma unroll
                        for (int kx = 0; kx < 3; ++kx) {
                            float wv = wp[ky * 3 + kx];
                            acc[c][0] += win[ky][kx]         * wv;
                            acc[c][1] += win[ky][kx + 1]     * wv;
                            acc[c][2] += win[ky + 1][kx]     * wv;
                            acc[c][3] += win[ky + 1][kx + 1] * wv;
                        }
                    }
                }
            }
            float* s2i = &sxs2[im][0];      // input image dead -> reuse as flat
            #pragma unroll
            for (int c = 0; c < 8; ++c) {
                float m = fmaxf(fmaxf(acc[c][0], acc[c][1]),
                                fmaxf(acc[c][2], acc[c][3]));
                s2i[(cg * 8 + c) * 49 + p] = fmaxf(m, 0.f);
            }
        }
    }
    __syncthreads();

    // ---- coalesced flat write
    for (int i = tid; i < 2 * 784; i += 256) {
        int im = i / 784;
        int j  = i - im * 784;
        flat_out[(size_t)img0 * 784 + i] = sxs2[im][j];
    }

    // ---- tiny heads: waves 0/1 = image, lanes 0..11
    {
        const int im   = __builtin_amdgcn_readfirstlane(tid >> 6);
        const int lane = tid & 63;
        if (im < 2 && lane < 12) {
            const float* s2i = &sxs2[im][0];
            const int gimg = img0 + im;
            const float f0 = s2i[0], f1 = s2i[1], f2 = s2i[2], f3 = s2i[3];
            const int off_samp = bsz * 4;
            const int off_reg  = bsz * 6;
            const int off_ker  = bsz * 7;
            if (lane < 10) {
                int j = lane;
                float m0 = mem[j * 4 + 0], m1 = mem[j * 4 + 1];
                float m2 = mem[j * 4 + 2], m3 = mem[j * 4 + 3];
                float sq = f0 * f0 + f1 * f1 + f2 * f2 + f3 * f3
                         + m0 * m0 + m1 * m1 + m2 * m2 + m3 * m3
                         - 2.f * (f0 * m0 + f1 * m1 + f2 * m2 + f3 * m3);
                out[off_ker + (size_t)gimg * 10 + j] = expf(-sq);
            } else if (lane == 10) {
                float t1[4];
                #pragma unroll
                for (int j = 0; j < 4; ++j)
                    t1[j] = tanhf(f0 * sw1[j * 2] + f1 * sw1[j * 2 + 1] + sb1[j]);
                float s0 = sb2[0], s1v = sb2[1];
                #pragma unroll
                for (int j = 0; j < 4; ++j) { s0 += t1[j] * sw2[j]; s1v += t1[j] * sw2[4 + j]; }
                float mx = fmaxf(s0, s1v);
                float e0 = expf(s0 - mx), e1 = expf(s1v - mx);
                float inv = 1.f / (e0 + e1);
                out[off_samp + (size_t)gimg * 2 + 0] = e0 * inv;
                out[off_samp + (size_t)gimg * 2 + 1] = e1 * inv;
            } else {
                float e1a[8];
                #pragma unroll
                for (int j = 0; j < 8; ++j)
                    e1a[j] = tanhf(f0 * ew1[j * 2] + f1 * ew1[j * 2 + 1] + eb1[j]);
                float rg = eb3[0];
                #pragma unroll
                for (int m = 0; m < 4; ++m) {
                    float a = eb2[m];
                    #pragma unroll
                    for (int j = 0; j < 8; ++j) a += e1a[j] * ew2[m * 8 + j];
                    rg += tanhf(a) * ew3[m];
                }
                out[off_reg + gimg] = rg;
            }
        }
    }
}

// ---------------------------------------------------------------------------
// Kernel 3: fc1 (784->64) + relu. grid = (bsz/64)*2, block = 64 img x 32 out
// ---------------------------------------------------------------------------
__global__ __launch_bounds__(256) void k_fc1(
    const float* __restrict__ flat, const float* __restrict__ wt,
    const float* __restrict__ fc1b, float* __restrict__ ht, int bsz)
{
    const int ib    = blockIdx.x >> 1;
    const int oh    = blockIdx.x & 1;
    const int lane  = threadIdx.x & 63;
    const int wv    = __builtin_amdgcn_readfirstlane(threadIdx.x >> 6);
    const int obase = oh * 32 + wv * 8;
    const int img   = ib * 64 + lane;
    const float* fr = flat + (size_t)img * 784;

    float acc[8];
    #pragma unroll
    for (int j = 0; j < 8; ++j) acc[j] = 0.f;

    for (int k = 0; k < 784; k += 4) {
        float4 f = *(const float4*)(fr + k);
        const float* fv = (const float*)&f;
        #pragma unroll
        for (int kk = 0; kk < 4; ++kk) {
            const float* wp = &wt[(k + kk) * 64 + obase];   // uniform -> s_load x8
            #pragma unroll
            for (int j = 0; j < 8; ++j) acc[j] += fv[kk] * wp[j];
        }
    }
    #pragma unroll
    for (int j = 0; j < 8; ++j)
        ht[(size_t)(obase + j) * bsz + img] = fmaxf(acc[j] + fc1b[obase + j], 0.f);
}

// ---------------------------------------------------------------------------
// Kernel 4: fc2 (64->4) from transposed ht -> transposed fct
// ---------------------------------------------------------------------------
__global__ __launch_bounds__(256) void k_fc2(
    const float* __restrict__ ht, const float* __restrict__ fc2w,
    const float* __restrict__ fc2b, float* __restrict__ fct, int bsz)
{
    const int img = blockIdx.x * 256 + threadIdx.x;
    float a0 = fc2b[0], a1 = fc2b[1], a2 = fc2b[2], a3 = fc2b[3];
    for (int o = 0; o < 64; ++o) {
        float hv = ht[(size_t)o * bsz + img];   // coalesced
        a0 += hv * fc2w[o];                     // uniform -> s_load
        a1 += hv * fc2w[64 + o];
        a2 += hv * fc2w[128 + o];
        a3 += hv * fc2w[192 + o];
    }
    fct[img]            = a0;
    fct[bsz + img]      = a1;
    fct[2 * bsz + img]  = a2;
    fct[3 * bsz + img]  = a3;
}

// ---------------------------------------------------------------------------
// Kernel 5: BN partials — 64 blocks, block = (channel, segment)
// ---------------------------------------------------------------------------
__global__ __launch_bounds__(256) void k_bnred1(
    const float* __restrict__ fct, float* __restrict__ partial, int bsz)
{
    const int tid = threadIdx.x;
    const int ch  = blockIdx.x & 3;
    const int seg = blockIdx.x >> 2;           // 16 segments per channel
    const int n   = bsz / 16;                  // 512
    const float* p = fct + (size_t)ch * bsz + seg * n;
    float s = 0.f, ss = 0.f;
    for (int i = tid; i < n; i += 256) {
        float v = p[i];
        s += v; ss += v * v;
    }
    __shared__ float rs[256], rss[256];
    rs[tid] = s; rss[tid] = ss;
    __syncthreads();
    for (int off = 128; off >= 1; off >>= 1) {
        if (tid < off) { rs[tid] += rs[tid + off]; rss[tid] += rss[tid + off]; }
        __syncthreads();
    }
    if (tid == 0) {
        partial[blockIdx.x * 2]     = rs[0];
        partial[blockIdx.x * 2 + 1] = rss[0];
    }
}

__global__ __launch_bounds__(64) void k_bnred2(
    const float* __restrict__ partial, const float* __restrict__ g,
    const float* __restrict__ bb, float* __restrict__ bnp, int bsz)
{
    const int tid = threadIdx.x;
    if (tid < 4) {
        float s = 0.f, ss = 0.f;
        for (int seg = 0; seg < 16; ++seg) {
            s  += partial[(seg * 4 + tid) * 2];
            ss += partial[(seg * 4 + tid) * 2 + 1];
        }
        float n = (float)bsz;
        float mu  = s / n;
        float var = ss / n - mu * mu;
        float scale = g[tid] * rsqrtf(var + EPS_BN);
        bnp[tid]     = scale;
        bnp[4 + tid] = bb[tid] - mu * scale;
    }
}

// ---------------------------------------------------------------------------
// Kernel 6: apply BN -> logits (out[img*4+c]), float4 store
// ---------------------------------------------------------------------------
__global__ __launch_bounds__(256) void k_bnapply(
    const float* __restrict__ fct, const float* __restrict__ bnp,
    float* __restrict__ out, int bsz)
{
    const int img = blockIdx.x * 256 + threadIdx.x;
    float4 r;
    r.x = fct[img]           * bnp[0] + bnp[4];
    r.y = fct[bsz + img]     * bnp[1] + bnp[5];
    r.z = fct[2 * bsz + img] * bnp[2] + bnp[6];
    r.w = fct[3 * bsz + img] * bnp[3] + bnp[7];
    *(float4*)(out + (size_t)img * 4) = r;
}

// ---------------------------------------------------------------------------
extern "C" void kernel_launch(void* const* d_in, const int* in_sizes, int n_in,
                              void* d_out, int out_size, void* d_ws, size_t ws_size,
                              hipStream_t stream) {
    const float* x     = (const float*)d_in[0];
    const float* c1w   = (const float*)d_in[1];
    const float* c1b   = (const float*)d_in[2];
    const float* c2w   = (const float*)d_in[3];
    const float* c2b   = (const float*)d_in[4];
    const float* fc1w  = (const float*)d_in[5];
    const float* fc1b  = (const float*)d_in[6];
    const float* fc2w  = (const float*)d_in[7];
    const float* fc2b  = (const float*)d_in[8];
    const float* bng   = (const float*)d_in[9];
    const float* bnb   = (const float*)d_in[10];
    const float* sw1   = (const float*)d_in[11];
    const float* sb1   = (const float*)d_in[12];
    const float* sw2   = (const float*)d_in[13];
    const float* sb2   = (const float*)d_in[14];
    const float* ew1   = (const float*)d_in[15];
    const float* eb1   = (const float*)d_in[16];
    const float* ew2   = (const float*)d_in[17];
    const float* eb2   = (const float*)d_in[18];
    const float* ew3   = (const float*)d_in[19];
    const float* eb3   = (const float*)d_in[20];
    const float* mem   = (const float*)d_in[21];

    const int bsz = in_sizes[0] / 784;         // 8192
    float* out = (float*)d_out;
    float* ws  = (float*)d_ws;

    float* wt      = ws;                               // 50176
    float* flat    = wt + 50176;                       // bsz*784
    float* ht      = flat + (size_t)bsz * 784;         // 64*bsz
    float* fct     = ht + (size_t)bsz * 64;            // 4*bsz
    float* partial = fct + (size_t)bsz * 4;            // 128
    float* bnp     = partial + 128;                    // 8

    k_transpose<<<196, 256, 0, stream>>>(fc1w, wt);
    k_conv<<<bsz / 2, 256, 0, stream>>>(x, c1w, c1b, c2w, c2b,
                                        sw1, sb1, sw2, sb2,
                                        ew1, eb1, ew2, eb2, ew3, eb3, mem,
                                        flat, out, bsz);
    k_fc1<<<(bsz / 64) * 2, 256, 0, stream>>>(flat, wt, fc1b, ht, bsz);
    k_fc2<<<bsz / 256, 256, 0, stream>>>(ht, fc2w, fc2b, fct, bsz);
    k_bnred1<<<64, 256, 0, stream>>>(fct, partial, bsz);
    k_bnred2<<<1, 64, 0, stream>>>(partial, bng, bnb, bnp, bsz);
    k_bnapply<<<bsz / 256, 256, 0, stream>>>(fct, bnp, out, bsz);
}

// Round 5
// 95.096 us; speedup vs baseline: 1.7491x; 1.7491x over previous
//
#include <hip/hip_runtime.h>
#include <math.h>

#define EPS_BN 1e-5f

typedef float  f32x4  __attribute__((ext_vector_type(4)));
typedef short  bf16x8 __attribute__((ext_vector_type(8)));

__device__ inline unsigned short f2bf(float f) {
    union { float f; unsigned u; } c; c.f = f;
    unsigned u = c.u;
    return (unsigned short)((u + 0x7FFFu + ((u >> 16) & 1u)) >> 16);  // RNE
}

// ---------------------------------------------------------------------------
// Kernel 1: pack fc1_w (64,784) into MFMA B-fragment layout, bf16, K pad 800
//   Bp[((kb*4 + nf)*64 + lane)*8 + j] = fc1_w[nf*16 + (lane&15)][kb*32+(lane>>4)*8+j]
// ---------------------------------------------------------------------------
__global__ __launch_bounds__(256) void k_prepB(const float* __restrict__ w,
                                               unsigned short* __restrict__ Bp) {
    int t = blockIdx.x * 256 + threadIdx.x;
    if (t < 25 * 4 * 64 * 8) {
        int j  = t & 7;
        int l  = (t >> 3) & 63;
        int nf = (t >> 9) & 3;
        int kb = t >> 11;
        int k  = kb * 32 + (l >> 4) * 8 + j;
        int o  = nf * 16 + (l & 15);
        float v = (k < 784) ? w[o * 784 + k] : 0.f;
        Bp[t] = f2bf(v);
    }
}

// ---------------------------------------------------------------------------
// Kernel 2: conv1+pool, conv2+pool, heads, bf16 flat write — 2 img/block
// ---------------------------------------------------------------------------
__global__ __launch_bounds__(256, 8) void k_conv(
    const float* __restrict__ x,
    const float* __restrict__ c1w, const float* __restrict__ c1b,
    const float* __restrict__ c2w, const float* __restrict__ c2b,
    const float* __restrict__ sw1, const float* __restrict__ sb1,
    const float* __restrict__ sw2, const float* __restrict__ sb2,
    const float* __restrict__ ew1, const float* __restrict__ eb1,
    const float* __restrict__ ew2, const float* __restrict__ eb2,
    const float* __restrict__ ew3, const float* __restrict__ eb3,
    const float* __restrict__ mem,
    unsigned short* __restrict__ flatb, float* __restrict__ out, int bsz)
{
    __shared__ float sxs2[2][812];     // input (pitch 29); later flat row (784)
    __shared__ float s1[2][8][210];    // pooled conv1: 14 rows x pitch 15

    const int tid  = threadIdx.x;
    const int img0 = blockIdx.x * 2;

    const float* xb = x + (size_t)img0 * 784;
    for (int i = tid; i < 2 * 784; i += 256) {
        int im = i / 784;
        int j  = i - im * 784;
        sxs2[im][(j / 28) * 29 + (j % 28)] = xb[i];
    }
    __syncthreads();

    // ---- conv1 (1->8) + relu + pool: 196 tasks = (img, py, px-pair)
    if (tid < 196) {
        int im  = tid / 98;
        int r   = tid - im * 98;
        int py  = r / 7;
        int pxq = r - py * 7;
        int br  = 2 * py - 1;
        int bc  = 4 * pxq - 1;
        const float* sp = &sxs2[im][0];
        float win[4][6];
        #pragma unroll
        for (int wy = 0; wy < 4; ++wy) {
            int iy = br + wy;
            bool oy = (unsigned)iy < 28u;
            #pragma unroll
            for (int wx = 0; wx < 6; ++wx) {
                int ix = bc + wx;
                win[wy][wx] = (oy && (unsigned)ix < 28u) ? sp[iy * 29 + ix] : 0.f;
            }
        }
        #pragma unroll
        for (int c = 0; c < 8; ++c) {
            const float* wp = &c1w[c * 9];
            float bb = c1b[c];
            float a[2][2][2];
            #pragma unroll
            for (int q = 0; q < 2; ++q)
                #pragma unroll
                for (int dy = 0; dy < 2; ++dy)
                    #pragma unroll
                    for (int dx = 0; dx < 2; ++dx) a[q][dy][dx] = bb;
            #pragma unroll
            for (int ky = 0; ky < 3; ++ky) {
                #pragma unroll
                for (int kx = 0; kx < 3; ++kx) {
                    float wv = wp[ky * 3 + kx];
                    #pragma unroll
                    for (int q = 0; q < 2; ++q)
                        #pragma unroll
                        for (int dy = 0; dy < 2; ++dy)
                            #pragma unroll
                            for (int dx = 0; dx < 2; ++dx)
                                a[q][dy][dx] += win[dy + ky][2 * q + dx + kx] * wv;
                }
            }
            #pragma unroll
            for (int q = 0; q < 2; ++q) {
                float m = fmaxf(fmaxf(a[q][0][0], a[q][0][1]),
                                fmaxf(a[q][1][0], a[q][1][1]));
                s1[im][c][py * 15 + 2 * pxq + q] = fmaxf(m, 0.f);
            }
        }
    }
    __syncthreads();

    // ---- conv2 (8->16) + relu + pool: wave=(img,cgroup), lane=position
    {
        const int im = __builtin_amdgcn_readfirstlane(tid >> 7);
        const int cg = __builtin_amdgcn_readfirstlane((tid >> 6) & 1);
        const int p  = tid & 63;
        if (p < 49) {
            int py = p / 7, px = p - py * 7;
            int br = 2 * py - 1, bc = 2 * px - 1;
            float acc[8][4];
            #pragma unroll
            for (int c = 0; c < 8; ++c) {
                float bb = c2b[cg * 8 + c];
                acc[c][0] = bb; acc[c][1] = bb; acc[c][2] = bb; acc[c][3] = bb;
            }
            for (int ic = 0; ic < 8; ++ic) {
                const float* sp = &s1[im][ic][0];
                float win[4][4];
                #pragma unroll
                for (int wy = 0; wy < 4; ++wy) {
                    int iy = br + wy;
                    bool oy = (unsigned)iy < 14u;
                    #pragma unroll
                    for (int wx = 0; wx < 4; ++wx) {
                        int ix = bc + wx;
                        win[wy][wx] = (oy && (unsigned)ix < 14u) ? sp[iy * 15 + ix] : 0.f;
                    }
                }
                #pragma unroll
                for (int c = 0; c < 8; ++c) {
                    const float* wp = &c2w[((cg * 8 + c) * 8 + ic) * 9];
                    #pragma unroll
                    for (int ky = 0; ky < 3; ++ky) {
                        #pragma unroll
                        for (int kx = 0; kx < 3; ++kx) {
                            float wv = wp[ky * 3 + kx];
                            acc[c][0] += win[ky][kx]         * wv;
                            acc[c][1] += win[ky][kx + 1]     * wv;
                            acc[c][2] += win[ky + 1][kx]     * wv;
                            acc[c][3] += win[ky + 1][kx + 1] * wv;
                        }
                    }
                }
            }
            float* s2i = &sxs2[im][0];
            #pragma unroll
            for (int c = 0; c < 8; ++c) {
                float m = fmaxf(fmaxf(acc[c][0], acc[c][1]),
                                fmaxf(acc[c][2], acc[c][3]));
                s2i[(cg * 8 + c) * 49 + p] = fmaxf(m, 0.f);
            }
        }
    }
    __syncthreads();

    // ---- bf16 flat write, rows padded to 800 (pack 2 bf16 -> 1 u32)
    for (int i = tid; i < 2 * 400; i += 256) {
        int im = i / 400;
        int j  = (i - im * 400) * 2;
        const float* s2i = &sxs2[im][0];
        float v0 = (j     < 784) ? s2i[j]     : 0.f;
        float v1 = (j + 1 < 784) ? s2i[j + 1] : 0.f;
        unsigned pk = (unsigned)f2bf(v0) | ((unsigned)f2bf(v1) << 16);
        *(unsigned*)(flatb + (size_t)(img0 + im) * 800 + j) = pk;
    }

    // ---- tiny heads (fp32 exact): waves 0/1 = image, lanes 0..11
    {
        const int im   = __builtin_amdgcn_readfirstlane(tid >> 6);
        const int lane = tid & 63;
        if (im < 2 && lane < 12) {
            const float* s2i = &sxs2[im][0];
            const int gimg = img0 + im;
            const float f0 = s2i[0], f1 = s2i[1], f2 = s2i[2], f3 = s2i[3];
            const int off_samp = bsz * 4;
            const int off_reg  = bsz * 6;
            const int off_ker  = bsz * 7;
            if (lane < 10) {
                int j = lane;
                float m0 = mem[j * 4 + 0], m1 = mem[j * 4 + 1];
                float m2 = mem[j * 4 + 2], m3 = mem[j * 4 + 3];
                float sq = f0 * f0 + f1 * f1 + f2 * f2 + f3 * f3
                         + m0 * m0 + m1 * m1 + m2 * m2 + m3 * m3
                         - 2.f * (f0 * m0 + f1 * m1 + f2 * m2 + f3 * m3);
                out[off_ker + (size_t)gimg * 10 + j] = expf(-sq);
            } else if (lane == 10) {
                float t1[4];
                #pragma unroll
                for (int j = 0; j < 4; ++j)
                    t1[j] = tanhf(f0 * sw1[j * 2] + f1 * sw1[j * 2 + 1] + sb1[j]);
                float s0 = sb2[0], s1v = sb2[1];
                #pragma unroll
                for (int j = 0; j < 4; ++j) { s0 += t1[j] * sw2[j]; s1v += t1[j] * sw2[4 + j]; }
                float mx = fmaxf(s0, s1v);
                float e0 = expf(s0 - mx), e1 = expf(s1v - mx);
                float inv = 1.f / (e0 + e1);
                out[off_samp + (size_t)gimg * 2 + 0] = e0 * inv;
                out[off_samp + (size_t)gimg * 2 + 1] = e1 * inv;
            } else {
                float e1a[8];
                #pragma unroll
                for (int j = 0; j < 8; ++j)
                    e1a[j] = tanhf(f0 * ew1[j * 2] + f1 * ew1[j * 2 + 1] + eb1[j]);
                float rg = eb3[0];
                #pragma unroll
                for (int m = 0; m < 4; ++m) {
                    float a = eb2[m];
                    #pragma unroll
                    for (int j = 0; j < 8; ++j) a += e1a[j] * ew2[m * 8 + j];
                    rg += tanhf(a) * ew3[m];
                }
                out[off_reg + gimg] = rg;
            }
        }
    }
}

// ---------------------------------------------------------------------------
// Kernel 3: fc1 (MFMA bf16, M=bsz N=64 K=800) + relu + fc2 fused -> fct[4][bsz]
//   block = 128 thr (2 waves x 16 imgs); grid = bsz/32
// ---------------------------------------------------------------------------
__global__ __launch_bounds__(128) void k_fc(
    const unsigned short* __restrict__ flatb, const unsigned short* __restrict__ Bp,
    const float* __restrict__ fc1b, const float* __restrict__ fc2w,
    const float* __restrict__ fc2b, float* __restrict__ fct, int bsz)
{
    __shared__ float h[2][16][68];

    const int tid  = threadIdx.x;
    const int w    = __builtin_amdgcn_readfirstlane(tid >> 6);
    const int l    = tid & 63;
    const int img0 = blockIdx.x * 32 + w * 16;
    const int m15  = l & 15;
    const int grp  = l >> 4;     // 0..3

    const unsigned short* aptr = flatb + (size_t)(img0 + m15) * 800 + grp * 8;
    const unsigned short* bptr = Bp + (size_t)l * 8;

    f32x4 acc[4] = {};
    for (int kb = 0; kb < 25; ++kb) {
        bf16x8 a = *(const bf16x8*)(aptr + kb * 32);
        #pragma unroll
        for (int nf = 0; nf < 4; ++nf) {
            bf16x8 b = *(const bf16x8*)(bptr + (size_t)(kb * 4 + nf) * 64 * 8);
            acc[nf] = __builtin_amdgcn_mfma_f32_16x16x32_bf16(a, b, acc[nf], 0, 0, 0);
        }
    }

    // epilogue: D lane mapping col=l&15, row=grp*4+r
    #pragma unroll
    for (int nf = 0; nf < 4; ++nf) {
        int j = nf * 16 + m15;
        float bj = fc1b[j];
        #pragma unroll
        for (int r = 0; r < 4; ++r)
            h[w][grp * 4 + r][j] = fmaxf(acc[nf][r] + bj, 0.f);
    }
    __syncthreads();

    // fc2: lane = (img, ch)
    {
        int im = m15, ch = grp;
        float a = fc2b[ch];
        const float* hp = &h[w][im][0];
        const float* wp = &fc2w[ch * 64];
        #pragma unroll 8
        for (int o = 0; o < 64; ++o) a += hp[o] * wp[o];
        fct[(size_t)ch * bsz + img0 + im] = a;
    }
}

// ---------------------------------------------------------------------------
// Kernel 4: BN partials — 64 blocks = (channel, segment)
// ---------------------------------------------------------------------------
__global__ __launch_bounds__(256) void k_bnred1(
    const float* __restrict__ fct, float* __restrict__ partial, int bsz)
{
    const int tid = threadIdx.x;
    const int ch  = blockIdx.x & 3;
    const int seg = blockIdx.x >> 2;
    const int n   = bsz / 16;
    const float* p = fct + (size_t)ch * bsz + seg * n;
    float s = 0.f, ss = 0.f;
    for (int i = tid; i < n; i += 256) {
        float v = p[i];
        s += v; ss += v * v;
    }
    __shared__ float rs[256], rss[256];
    rs[tid] = s; rss[tid] = ss;
    __syncthreads();
    for (int off = 128; off >= 1; off >>= 1) {
        if (tid < off) { rs[tid] += rs[tid + off]; rss[tid] += rss[tid + off]; }
        __syncthreads();
    }
    if (tid == 0) {
        partial[blockIdx.x * 2]     = rs[0];
        partial[blockIdx.x * 2 + 1] = rss[0];
    }
}

__global__ __launch_bounds__(64) void k_bnred2(
    const float* __restrict__ partial, const float* __restrict__ g,
    const float* __restrict__ bb, float* __restrict__ bnp, int bsz)
{
    const int tid = threadIdx.x;
    if (tid < 4) {
        float s = 0.f, ss = 0.f;
        for (int seg = 0; seg < 16; ++seg) {
            s  += partial[(seg * 4 + tid) * 2];
            ss += partial[(seg * 4 + tid) * 2 + 1];
        }
        float n = (float)bsz;
        float mu  = s / n;
        float var = ss / n - mu * mu;
        float scale = g[tid] * rsqrtf(var + EPS_BN);
        bnp[tid]     = scale;
        bnp[4 + tid] = bb[tid] - mu * scale;
    }
}

// ---------------------------------------------------------------------------
// Kernel 5: apply BN -> logits, float4 store
// ---------------------------------------------------------------------------
__global__ __launch_bounds__(256) void k_bnapply(
    const float* __restrict__ fct, const float* __restrict__ bnp,
    float* __restrict__ out, int bsz)
{
    const int img = blockIdx.x * 256 + threadIdx.x;
    float4 r;
    r.x = fct[img]           * bnp[0] + bnp[4];
    r.y = fct[bsz + img]     * bnp[1] + bnp[5];
    r.z = fct[2 * bsz + img] * bnp[2] + bnp[6];
    r.w = fct[3 * bsz + img] * bnp[3] + bnp[7];
    *(float4*)(out + (size_t)img * 4) = r;
}

// ---------------------------------------------------------------------------
extern "C" void kernel_launch(void* const* d_in, const int* in_sizes, int n_in,
                              void* d_out, int out_size, void* d_ws, size_t ws_size,
                              hipStream_t stream) {
    const float* x     = (const float*)d_in[0];
    const float* c1w   = (const float*)d_in[1];
    const float* c1b   = (const float*)d_in[2];
    const float* c2w   = (const float*)d_in[3];
    const float* c2b   = (const float*)d_in[4];
    const float* fc1w  = (const float*)d_in[5];
    const float* fc1b  = (const float*)d_in[6];
    const float* fc2w  = (const float*)d_in[7];
    const float* fc2b  = (const float*)d_in[8];
    const float* bng   = (const float*)d_in[9];
    const float* bnb   = (const float*)d_in[10];
    const float* sw1   = (const float*)d_in[11];
    const float* sb1   = (const float*)d_in[12];
    const float* sw2   = (const float*)d_in[13];
    const float* sb2   = (const float*)d_in[14];
    const float* ew1   = (const float*)d_in[15];
    const float* eb1   = (const float*)d_in[16];
    const float* ew2   = (const float*)d_in[17];
    const float* eb2   = (const float*)d_in[18];
    const float* ew3   = (const float*)d_in[19];
    const float* eb3   = (const float*)d_in[20];
    const float* mem   = (const float*)d_in[21];

    const int bsz = in_sizes[0] / 784;         // 8192
    float* out = (float*)d_out;

    unsigned short* flatb = (unsigned short*)d_ws;           // bsz*800 bf16
    unsigned short* Bp    = flatb + (size_t)bsz * 800;       // 51200 bf16
    float* fct            = (float*)(Bp + 51200);            // 4*bsz
    float* partial        = fct + (size_t)bsz * 4;           // 128
    float* bnp            = partial + 128;                   // 8

    k_prepB<<<200, 256, 0, stream>>>(fc1w, Bp);
    k_conv<<<bsz / 2, 256, 0, stream>>>(x, c1w, c1b, c2w, c2b,
                                        sw1, sb1, sw2, sb2,
                                        ew1, eb1, ew2, eb2, ew3, eb3, mem,
                                        flatb, out, bsz);
    k_fc<<<bsz / 32, 128, 0, stream>>>(flatb, Bp, fc1b, fc2w, fc2b, fct, bsz);
    k_bnred1<<<64, 256, 0, stream>>>(fct, partial, bsz);
    k_bnred2<<<1, 64, 0, stream>>>(partial, bng, bnb, bnp, bsz);
    k_bnapply<<<bsz / 256, 256, 0, stream>>>(fct, bnp, out, bsz);
}

// Round 6
// 91.239 us; speedup vs baseline: 1.8230x; 1.0423x over previous
//
#include <hip/hip_runtime.h>
#include <math.h>

#define EPS_BN 1e-5f

typedef float  f32x4  __attribute__((ext_vector_type(4)));
typedef short  bf16x8 __attribute__((ext_vector_type(8)));

__device__ inline unsigned short f2bf(float f) {
    union { float f; unsigned u; } c; c.f = f;
    unsigned u = c.u;
    return (unsigned short)((u + 0x7FFFu + ((u >> 16) & 1u)) >> 16);  // RNE
}

// ---------------------------------------------------------------------------
// Kernel 1: pack fc1_w (64,784) into MFMA B-fragment layout, bf16, K pad 800
// ---------------------------------------------------------------------------
__global__ __launch_bounds__(256) void k_prepB(const float* __restrict__ w,
                                               unsigned short* __restrict__ Bp) {
    int t = blockIdx.x * 256 + threadIdx.x;
    if (t < 25 * 4 * 64 * 8) {
        int j  = t & 7;
        int l  = (t >> 3) & 63;
        int nf = (t >> 9) & 3;
        int kb = t >> 11;
        int k  = kb * 32 + (l >> 4) * 8 + j;
        int o  = nf * 16 + (l & 15);
        float v = (k < 784) ? w[o * 784 + k] : 0.f;
        Bp[t] = f2bf(v);
    }
}

// ---------------------------------------------------------------------------
// Kernel 2: conv1+pool, conv2+pool, heads, bf16 flat — 2 img/block, halo LDS
// ---------------------------------------------------------------------------
__global__ __launch_bounds__(256, 6) void k_conv(
    const float* __restrict__ x,
    const float* __restrict__ c1w, const float* __restrict__ c1b,
    const float* __restrict__ c2w, const float* __restrict__ c2b,
    const float* __restrict__ sw1, const float* __restrict__ sb1,
    const float* __restrict__ sw2, const float* __restrict__ sb2,
    const float* __restrict__ ew1, const float* __restrict__ eb1,
    const float* __restrict__ ew2, const float* __restrict__ eb2,
    const float* __restrict__ ew3, const float* __restrict__ eb3,
    const float* __restrict__ mem,
    unsigned short* __restrict__ flatb, float* __restrict__ out, int bsz)
{
    __shared__ float sx[2][900];            // 30x30 zero-halo input; later s2/flat
    __shared__ float s1[2][8][16][18];      // zero-halo pooled conv1 (interior +1)

    const int tid  = threadIdx.x;
    const int img0 = blockIdx.x * 2;

    // ---- zero input halo (232 cells, 1/thread)
    if (tid < 232) {
        int im = tid / 116;
        int r  = tid - im * 116;
        int idx;
        if      (r < 30) idx = r;                     // row 0
        else if (r < 60) idx = 29 * 30 + (r - 30);    // row 29
        else if (r < 88) idx = (r - 60 + 1) * 30;     // col 0, rows 1..28
        else             idx = (r - 88 + 1) * 30 + 29;// col 29, rows 1..28
        sx[im][idx] = 0.f;
    }
    // ---- stage interior (coalesced)
    const float* xb = x + (size_t)img0 * 784;
    for (int i = tid; i < 1568; i += 256) {
        int im = i / 784;
        int j  = i - im * 784;
        sx[im][(j / 28 + 1) * 30 + (j % 28) + 1] = xb[i];
    }
    __syncthreads();

    // ---- zero s1 halo (1024 cells, 4/thread)
    for (int q = tid; q < 1024; q += 256) {
        int imc = q >> 6;            // im*8+ic
        int r   = q & 63;
        int idx;
        if      (r < 18) idx = r;                      // row 0
        else if (r < 36) idx = 15 * 18 + (r - 18);     // row 15
        else if (r < 50) idx = (r - 36 + 1) * 18;      // col 0, rows 1..14
        else             idx = (r - 50 + 1) * 18 + 15; // col 15, rows 1..14
        ((float*)s1)[imc * 288 + idx] = 0.f;
    }

    // ---- conv1 (1->8) + relu + pool: 196 tasks = (img, py, px-pair), no bounds
    if (tid < 196) {
        int im  = tid / 98;
        int r   = tid - im * 98;
        int py  = r / 7;
        int pxq = r - py * 7;
        const float* sp = &sx[im][(2 * py) * 30 + 4 * pxq];  // halo base
        float win[4][6];
        #pragma unroll
        for (int wy = 0; wy < 4; ++wy) {
            #pragma unroll
            for (int t = 0; t < 3; ++t) {
                float2 v = *(const float2*)(sp + wy * 30 + 2 * t);
                win[wy][2 * t]     = v.x;
                win[wy][2 * t + 1] = v.y;
            }
        }
        #pragma unroll
        for (int c = 0; c < 8; ++c) {
            const float* wp = &c1w[c * 9];            // uniform -> s_load
            float bb = c1b[c];
            float a[2][2][2];
            #pragma unroll
            for (int q = 0; q < 2; ++q)
                #pragma unroll
                for (int dy = 0; dy < 2; ++dy)
                    #pragma unroll
                    for (int dx = 0; dx < 2; ++dx) a[q][dy][dx] = bb;
            #pragma unroll
            for (int ky = 0; ky < 3; ++ky) {
                #pragma unroll
                for (int kx = 0; kx < 3; ++kx) {
                    float wv = wp[ky * 3 + kx];
                    #pragma unroll
                    for (int q = 0; q < 2; ++q)
                        #pragma unroll
                        for (int dy = 0; dy < 2; ++dy)
                            #pragma unroll
                            for (int dx = 0; dx < 2; ++dx)
                                a[q][dy][dx] += win[dy + ky][2 * q + dx + kx] * wv;
                }
            }
            #pragma unroll
            for (int q = 0; q < 2; ++q) {
                float m = fmaxf(fmaxf(a[q][0][0], a[q][0][1]),
                                fmaxf(a[q][1][0], a[q][1][1]));
                s1[im][c][py + 1][2 * pxq + 1 + q] = fmaxf(m, 0.f);
            }
        }
    }
    __syncthreads();

    // ---- conv2 (8->16) + relu + pool: wave=(img,cgroup), lane=pos, no bounds
    {
        const int im = __builtin_amdgcn_readfirstlane(tid >> 7);
        const int cg = __builtin_amdgcn_readfirstlane((tid >> 6) & 1);
        const int p  = tid & 63;
        if (p < 49) {
            int py = p / 7, px = p - py * 7;
            const float* sp = &s1[im][0][2 * py][2 * px];   // halo base, ic via +288
            float acc[8][4];
            #pragma unroll
            for (int c = 0; c < 8; ++c) {
                float bb = c2b[cg * 8 + c];
                acc[c][0] = bb; acc[c][1] = bb; acc[c][2] = bb; acc[c][3] = bb;
            }
            for (int ic = 0; ic < 8; ++ic) {
                float win[4][4];
                #pragma unroll
                for (int wy = 0; wy < 4; ++wy) {
                    float2 v0 = *(const float2*)(sp + ic * 288 + wy * 18);
                    float2 v1 = *(const float2*)(sp + ic * 288 + wy * 18 + 2);
                    win[wy][0] = v0.x; win[wy][1] = v0.y;
                    win[wy][2] = v1.x; win[wy][3] = v1.y;
                }
                #pragma unroll
                for (int c = 0; c < 8; ++c) {
                    const float* wp = &c2w[((cg * 8 + c) * 8 + ic) * 9];  // s_load
                    #pragma unroll
                    for (int ky = 0; ky < 3; ++ky) {
                        #pragma unroll
                        for (int kx = 0; kx < 3; ++kx) {
                            float wv = wp[ky * 3 + kx];
                            acc[c][0] += win[ky][kx]         * wv;
                            acc[c][1] += win[ky][kx + 1]     * wv;
                            acc[c][2] += win[ky + 1][kx]     * wv;
                            acc[c][3] += win[ky + 1][kx + 1] * wv;
                        }
                    }
                }
            }
            float* s2i = &sx[im][0];      // input dead -> reuse as flat row
            #pragma unroll
            for (int c = 0; c < 8; ++c) {
                float m = fmaxf(fmaxf(acc[c][0], acc[c][1]),
                                fmaxf(acc[c][2], acc[c][3]));
                s2i[(cg * 8 + c) * 49 + p] = fmaxf(m, 0.f);
            }
        }
    }
    __syncthreads();

    // ---- bf16 flat write, rows padded to 800 (pack 2 bf16 -> u32)
    for (int i = tid; i < 2 * 400; i += 256) {
        int im = i / 400;
        int j  = (i - im * 400) * 2;
        const float* s2i = &sx[im][0];
        float v0 = (j     < 784) ? s2i[j]     : 0.f;
        float v1 = (j + 1 < 784) ? s2i[j + 1] : 0.f;
        unsigned pk = (unsigned)f2bf(v0) | ((unsigned)f2bf(v1) << 16);
        *(unsigned*)(flatb + (size_t)(img0 + im) * 800 + j) = pk;
    }

    // ---- tiny heads (fp32 exact): one divergence-free path per wave
    {
        const int wv   = __builtin_amdgcn_readfirstlane(tid >> 6);
        const int lane = tid & 63;
        const int off_samp = bsz * 4;
        const int off_reg  = bsz * 6;
        const int off_ker  = bsz * 7;
        if (wv < 2) {                       // RBF kernel row, im = wv
            if (lane < 10) {
                const float* s2i = &sx[wv][0];
                const int gimg = img0 + wv;
                float f0 = s2i[0], f1 = s2i[1], f2 = s2i[2], f3 = s2i[3];
                float m0 = mem[lane * 4 + 0], m1 = mem[lane * 4 + 1];
                float m2 = mem[lane * 4 + 2], m3 = mem[lane * 4 + 3];
                float sq = f0 * f0 + f1 * f1 + f2 * f2 + f3 * f3
                         + m0 * m0 + m1 * m1 + m2 * m2 + m3 * m3
                         - 2.f * (f0 * m0 + f1 * m1 + f2 * m2 + f3 * m3);
                out[off_ker + (size_t)gimg * 10 + lane] = expf(-sq);
            }
        } else if (wv == 2) {               // sampler, im = lane (0,1)
            if (lane < 2) {
                const float* s2i = &sx[lane][0];
                const int gimg = img0 + lane;
                float f0 = s2i[0], f1 = s2i[1];
                float t1[4];
                #pragma unroll
                for (int j = 0; j < 4; ++j)
                    t1[j] = tanhf(f0 * sw1[j * 2] + f1 * sw1[j * 2 + 1] + sb1[j]);
                float s0 = sb2[0], s1v = sb2[1];
                #pragma unroll
                for (int j = 0; j < 4; ++j) { s0 += t1[j] * sw2[j]; s1v += t1[j] * sw2[4 + j]; }
                float mx = fmaxf(s0, s1v);
                float e0 = expf(s0 - mx), e1 = expf(s1v - mx);
                float inv = 1.f / (e0 + e1);
                out[off_samp + (size_t)gimg * 2 + 0] = e0 * inv;
                out[off_samp + (size_t)gimg * 2 + 1] = e1 * inv;
            }
        } else {                            // estimator, im = lane (0,1)
            if (lane < 2) {
                const float* s2i = &sx[lane][0];
                const int gimg = img0 + lane;
                float f0 = s2i[0], f1 = s2i[1];
                float e1a[8];
                #pragma unroll
                for (int j = 0; j < 8; ++j)
                    e1a[j] = tanhf(f0 * ew1[j * 2] + f1 * ew1[j * 2 + 1] + eb1[j]);
                float rg = eb3[0];
                #pragma unroll
                for (int m = 0; m < 4; ++m) {
                    float a = eb2[m];
                    #pragma unroll
                    for (int j = 0; j < 8; ++j) a += e1a[j] * ew2[m * 8 + j];
                    rg += tanhf(a) * ew3[m];
                }
                out[off_reg + gimg] = rg;
            }
        }
    }
}

// ---------------------------------------------------------------------------
// Kernel 3: fc1 (MFMA bf16, M=bsz N=64 K=800) + relu + fc2 fused -> fct[4][bsz]
// ---------------------------------------------------------------------------
__global__ __launch_bounds__(128) void k_fc(
    const unsigned short* __restrict__ flatb, const unsigned short* __restrict__ Bp,
    const float* __restrict__ fc1b, const float* __restrict__ fc2w,
    const float* __restrict__ fc2b, float* __restrict__ fct, int bsz)
{
    __shared__ float h[2][16][68];

    const int tid  = threadIdx.x;
    const int w    = __builtin_amdgcn_readfirstlane(tid >> 6);
    const int l    = tid & 63;
    const int img0 = blockIdx.x * 32 + w * 16;
    const int m15  = l & 15;
    const int grp  = l >> 4;

    const unsigned short* aptr = flatb + (size_t)(img0 + m15) * 800 + grp * 8;
    const unsigned short* bptr = Bp + (size_t)l * 8;

    f32x4 acc[4] = {};
    for (int kb = 0; kb < 25; ++kb) {
        bf16x8 a = *(const bf16x8*)(aptr + kb * 32);
        #pragma unroll
        for (int nf = 0; nf < 4; ++nf) {
            bf16x8 b = *(const bf16x8*)(bptr + (size_t)(kb * 4 + nf) * 64 * 8);
            acc[nf] = __builtin_amdgcn_mfma_f32_16x16x32_bf16(a, b, acc[nf], 0, 0, 0);
        }
    }

    #pragma unroll
    for (int nf = 0; nf < 4; ++nf) {
        int j = nf * 16 + m15;
        float bj = fc1b[j];
        #pragma unroll
        for (int r = 0; r < 4; ++r)
            h[w][grp * 4 + r][j] = fmaxf(acc[nf][r] + bj, 0.f);
    }
    __syncthreads();

    {
        int im = m15, ch = grp;
        float a = fc2b[ch];
        const float* hp = &h[w][im][0];
        const float* wp = &fc2w[ch * 64];
        #pragma unroll 8
        for (int o = 0; o < 64; ++o) a += hp[o] * wp[o];
        fct[(size_t)ch * bsz + img0 + im] = a;
    }
}

// ---------------------------------------------------------------------------
// Kernel 4: BN partials — 64 blocks = (channel, segment)
// ---------------------------------------------------------------------------
__global__ __launch_bounds__(256) void k_bnred1(
    const float* __restrict__ fct, float* __restrict__ partial, int bsz)
{
    const int tid = threadIdx.x;
    const int ch  = blockIdx.x & 3;
    const int seg = blockIdx.x >> 2;
    const int n   = bsz / 16;
    const float* p = fct + (size_t)ch * bsz + seg * n;
    float s = 0.f, ss = 0.f;
    for (int i = tid; i < n; i += 256) {
        float v = p[i];
        s += v; ss += v * v;
    }
    __shared__ float rs[256], rss[256];
    rs[tid] = s; rss[tid] = ss;
    __syncthreads();
    for (int off = 128; off >= 1; off >>= 1) {
        if (tid < off) { rs[tid] += rs[tid + off]; rss[tid] += rss[tid + off]; }
        __syncthreads();
    }
    if (tid == 0) {
        partial[blockIdx.x * 2]     = rs[0];
        partial[blockIdx.x * 2 + 1] = rss[0];
    }
}

__global__ __launch_bounds__(64) void k_bnred2(
    const float* __restrict__ partial, const float* __restrict__ g,
    const float* __restrict__ bb, float* __restrict__ bnp, int bsz)
{
    const int tid = threadIdx.x;
    if (tid < 4) {
        float s = 0.f, ss = 0.f;
        for (int seg = 0; seg < 16; ++seg) {
            s  += partial[(seg * 4 + tid) * 2];
            ss += partial[(seg * 4 + tid) * 2 + 1];
        }
        float n = (float)bsz;
        float mu  = s / n;
        float var = ss / n - mu * mu;
        float scale = g[tid] * rsqrtf(var + EPS_BN);
        bnp[tid]     = scale;
        bnp[4 + tid] = bb[tid] - mu * scale;
    }
}

// ---------------------------------------------------------------------------
// Kernel 5: apply BN -> logits, float4 store
// ---------------------------------------------------------------------------
__global__ __launch_bounds__(256) void k_bnapply(
    const float* __restrict__ fct, const float* __restrict__ bnp,
    float* __restrict__ out, int bsz)
{
    const int img = blockIdx.x * 256 + threadIdx.x;
    float4 r;
    r.x = fct[img]           * bnp[0] + bnp[4];
    r.y = fct[bsz + img]     * bnp[1] + bnp[5];
    r.z = fct[2 * bsz + img] * bnp[2] + bnp[6];
    r.w = fct[3 * bsz + img] * bnp[3] + bnp[7];
    *(float4*)(out + (size_t)img * 4) = r;
}

// ---------------------------------------------------------------------------
extern "C" void kernel_launch(void* const* d_in, const int* in_sizes, int n_in,
                              void* d_out, int out_size, void* d_ws, size_t ws_size,
                              hipStream_t stream) {
    const float* x     = (const float*)d_in[0];
    const float* c1w   = (const float*)d_in[1];
    const float* c1b   = (const float*)d_in[2];
    const float* c2w   = (const float*)d_in[3];
    const float* c2b   = (const float*)d_in[4];
    const float* fc1w  = (const float*)d_in[5];
    const float* fc1b  = (const float*)d_in[6];
    const float* fc2w  = (const float*)d_in[7];
    const float* fc2b  = (const float*)d_in[8];
    const float* bng   = (const float*)d_in[9];
    const float* bnb   = (const float*)d_in[10];
    const float* sw1   = (const float*)d_in[11];
    const float* sb1   = (const float*)d_in[12];
    const float* sw2   = (const float*)d_in[13];
    const float* sb2   = (const float*)d_in[14];
    const float* ew1   = (const float*)d_in[15];
    const float* eb1   = (const float*)d_in[16];
    const float* ew2   = (const float*)d_in[17];
    const float* eb2   = (const float*)d_in[18];
    const float* ew3   = (const float*)d_in[19];
    const float* eb3   = (const float*)d_in[20];
    const float* mem   = (const float*)d_in[21];

    const int bsz = in_sizes[0] / 784;         // 8192
    float* out = (float*)d_out;

    unsigned short* flatb = (unsigned short*)d_ws;           // bsz*800 bf16
    unsigned short* Bp    = flatb + (size_t)bsz * 800;       // 51200 bf16
    float* fct            = (float*)(Bp + 51200);            // 4*bsz
    float* partial        = fct + (size_t)bsz * 4;           // 128
    float* bnp            = partial + 128;                   // 8

    k_prepB<<<200, 256, 0, stream>>>(fc1w, Bp);
    k_conv<<<bsz / 2, 256, 0, stream>>>(x, c1w, c1b, c2w, c2b,
                                        sw1, sb1, sw2, sb2,
                                        ew1, eb1, ew2, eb2, ew3, eb3, mem,
                                        flatb, out, bsz);
    k_fc<<<bsz / 32, 128, 0, stream>>>(flatb, Bp, fc1b, fc2w, fc2b, fct, bsz);
    k_bnred1<<<64, 256, 0, stream>>>(fct, partial, bsz);
    k_bnred2<<<1, 64, 0, stream>>>(partial, bng, bnb, bnp, bsz);
    k_bnapply<<<bsz / 256, 256, 0, stream>>>(fct, bnp, out, bsz);
}

// Round 7
// 62.808 us; speedup vs baseline: 2.6482x; 1.4527x over previous
//
#include <hip/hip_runtime.h>
#include <math.h>

#define EPS_BN 1e-5f

typedef float  f32x4  __attribute__((ext_vector_type(4)));
typedef short  bf16x8 __attribute__((ext_vector_type(8)));

__device__ inline unsigned short f2bf(float f) {
    union { float f; unsigned u; } c; c.f = f;
    unsigned u = c.u;
    return (unsigned short)((u + 0x7FFFu + ((u >> 16) & 1u)) >> 16);  // RNE
}

// ---------------------------------------------------------------------------
// Kernel 1: weight packs.
//   blocks 0..199 : fc1_w -> Bp   (MFMA B-frag, K padded 784->800)
//   block  200    : conv2_w -> Bc2 (3 K-groups of 4kpos x 8ic, kpos 9..11 = 0)
// ---------------------------------------------------------------------------
__global__ __launch_bounds__(256) void k_prep(const float* __restrict__ fc1w,
                                              const float* __restrict__ c2w,
                                              unsigned short* __restrict__ Bp,
                                              unsigned short* __restrict__ Bc2) {
    if (blockIdx.x < 200) {
        int t = blockIdx.x * 256 + threadIdx.x;   // < 51200
        int j  = t & 7;
        int l  = (t >> 3) & 63;
        int nf = (t >> 9) & 3;
        int kb = t >> 11;
        int k  = kb * 32 + (l >> 4) * 8 + j;
        int o  = nf * 16 + (l & 15);
        float v = (k < 784) ? fc1w[o * 784 + k] : 0.f;
        Bp[t] = f2bf(v);
    } else {
        for (int t = threadIdx.x; t < 1536; t += 256) {
            int j  = t & 7;            // ic
            int l  = (t >> 3) & 63;
            int g  = t >> 9;           // k-group
            int kp = 4 * g + (l >> 4); // kernel position
            int oc = l & 15;
            float v = (kp < 9) ? c2w[(oc * 8 + j) * 9 + kp] : 0.f;
            Bc2[t] = f2bf(v);
        }
    }
}

// ---------------------------------------------------------------------------
// Kernel 2: conv1(vector) + conv2(MFMA) + exact heads + bf16 flat — 2 img/blk
// ---------------------------------------------------------------------------
__global__ __launch_bounds__(256, 8) void k_conv(
    const float* __restrict__ x,
    const float* __restrict__ c1w, const float* __restrict__ c1b,
    const float* __restrict__ c2w, const float* __restrict__ c2b,
    const unsigned short* __restrict__ Bc2,
    const float* __restrict__ sw1, const float* __restrict__ sb1,
    const float* __restrict__ sw2, const float* __restrict__ sb2,
    const float* __restrict__ ew1, const float* __restrict__ eb1,
    const float* __restrict__ ew2, const float* __restrict__ eb2,
    const float* __restrict__ ew3, const float* __restrict__ eb3,
    const float* __restrict__ mem,
    unsigned short* __restrict__ flatb, float* __restrict__ out, int bsz)
{
    __shared__ float sx[2][900];                          // 30x30 halo input; later flat
    __shared__ __align__(16) unsigned short s1t[2][16][16][8]; // bf16 conv1 out, halo
    __shared__ float s1f[2][4][12][8];                    // f32 corner of s1 for heads
    __shared__ float exact4[2][4];                        // exact flat[:4]

    const int tid  = threadIdx.x;
    const int img0 = blockIdx.x * 2;

    // ---- zero input halo
    if (tid < 232) {
        int im = tid / 116;
        int r  = tid - im * 116;
        int idx;
        if      (r < 30) idx = r;
        else if (r < 60) idx = 29 * 30 + (r - 30);
        else if (r < 88) idx = (r - 60 + 1) * 30;
        else             idx = (r - 88 + 1) * 30 + 29;
        sx[im][idx] = 0.f;
    }
    // ---- stage interior
    const float* xb = x + (size_t)img0 * 784;
    for (int i = tid; i < 1568; i += 256) {
        int im = i / 784;
        int j  = i - im * 784;
        sx[im][(j / 28 + 1) * 30 + (j % 28) + 1] = xb[i];
    }
    // ---- zero s1t halo (120 cells x 16B)
    for (int q = tid; q < 120; q += 256) {
        int im = q / 60, r = q - im * 60;
        int Y, X;
        if      (r < 16) { Y = 0;          X = r; }
        else if (r < 32) { Y = 15;         X = r - 16; }
        else if (r < 46) { Y = r - 32 + 1; X = 0; }
        else             { Y = r - 46 + 1; X = 15; }
        *(uint4*)&s1t[im][Y][X][0] = make_uint4(0, 0, 0, 0);
    }
    // ---- zero s1f (192 float4)
    for (int q = tid; q < 192; q += 256) ((float4*)s1f)[q] = make_float4(0, 0, 0, 0);
    __syncthreads();

    // ---- conv1 (1->8) + relu + pool: 196 tasks = (img, py, px-pair)
    if (tid < 196) {
        int im  = tid / 98;
        int r   = tid - im * 98;
        int py  = r / 7;
        int pxq = r - py * 7;
        const float* sp = &sx[im][(2 * py) * 30 + 4 * pxq];
        float win[4][6];
        #pragma unroll
        for (int wy = 0; wy < 4; ++wy) {
            #pragma unroll
            for (int t = 0; t < 3; ++t) {
                float2 v = *(const float2*)(sp + wy * 30 + 2 * t);
                win[wy][2 * t]     = v.x;
                win[wy][2 * t + 1] = v.y;
            }
        }
        unsigned pk0[4] = {0, 0, 0, 0}, pk1[4] = {0, 0, 0, 0};
        const bool sf = (py <= 2) && (pxq <= 4);
        #pragma unroll
        for (int c = 0; c < 8; ++c) {
            const float* wp = &c1w[c * 9];            // uniform -> s_load
            float bb = c1b[c];
            float a[2][2][2];
            #pragma unroll
            for (int q = 0; q < 2; ++q)
                #pragma unroll
                for (int dy = 0; dy < 2; ++dy)
                    #pragma unroll
                    for (int dx = 0; dx < 2; ++dx) a[q][dy][dx] = bb;
            #pragma unroll
            for (int ky = 0; ky < 3; ++ky) {
                #pragma unroll
                for (int kx = 0; kx < 3; ++kx) {
                    float wv = wp[ky * 3 + kx];
                    #pragma unroll
                    for (int q = 0; q < 2; ++q)
                        #pragma unroll
                        for (int dy = 0; dy < 2; ++dy)
                            #pragma unroll
                            for (int dx = 0; dx < 2; ++dx)
                                a[q][dy][dx] += win[dy + ky][2 * q + dx + kx] * wv;
                }
            }
            float v0 = fmaxf(fmaxf(fmaxf(a[0][0][0], a[0][0][1]),
                                   fmaxf(a[0][1][0], a[0][1][1])), 0.f);
            float v1 = fmaxf(fmaxf(fmaxf(a[1][0][0], a[1][0][1]),
                                   fmaxf(a[1][1][0], a[1][1][1])), 0.f);
            pk0[c >> 1] |= (unsigned)f2bf(v0) << ((c & 1) * 16);
            pk1[c >> 1] |= (unsigned)f2bf(v1) << ((c & 1) * 16);
            if (sf) {
                s1f[im][py + 1][2 * pxq + 1][c] = v0;
                s1f[im][py + 1][2 * pxq + 2][c] = v1;
            }
        }
        *(uint4*)&s1t[im][py + 1][2 * pxq + 1][0] = make_uint4(pk0[0], pk0[1], pk0[2], pk0[3]);
        *(uint4*)&s1t[im][py + 1][2 * pxq + 2][0] = make_uint4(pk1[0], pk1[1], pk1[2], pk1[3]);
    }
    __syncthreads();

    // ---- conv2 (8->16) + relu + pool via MFMA, quad-major M ordering
    {
        const int wv   = __builtin_amdgcn_readfirstlane(tid >> 6);
        const int im   = wv >> 1;
        const int half = wv & 1;
        const int l    = tid & 63;
        const int grp  = l >> 4;
        const int m15  = l & 15;

        bf16x8 bfr[3];
        #pragma unroll
        for (int g = 0; g < 3; ++g)
            bfr[g] = *(const bf16x8*)(Bc2 + (size_t)(g * 64 + l) * 8);

        int koff[3];
        #pragma unroll
        for (int g = 0; g < 3; ++g) {
            int kp = 4 * g + grp;
            koff[g] = (kp < 9) ? ((kp / 3) * 16 + (kp % 3)) * 8 : 0;
        }
        const float bias = c2b[m15];
        float* s2i = &sx[im][0];                 // input dead -> flat row

        for (int t = half; t < 13; t += 2) {
            int qa = 4 * t + (m15 >> 2);
            if (qa > 48) qa = 48;                // pad rows replicate row q=48
            int s  = m15 & 3;
            int py = qa / 7, px = qa - 7 * py;
            int y  = 2 * py + (s >> 1), xx = 2 * px + (s & 1);
            const unsigned short* ab = &s1t[im][y][xx][0];
            f32x4 acc = {};
            #pragma unroll
            for (int g = 0; g < 3; ++g) {
                bf16x8 a = *(const bf16x8*)(ab + koff[g]);
                acc = __builtin_amdgcn_mfma_f32_16x16x32_bf16(a, bfr[g], acc, 0, 0, 0);
            }
            float m = fmaxf(fmaxf(acc[0], acc[1]), fmaxf(acc[2], acc[3]));
            float val = fmaxf(m + bias, 0.f);
            int qo = 4 * t + grp;                // lane's output quad
            if (qo < 49) s2i[m15 * 49 + qo] = val;
        }

        // ---- exact fp32 flat[:4] (ch 0, quads 0..3) on waves 1,3 lanes 0..15
        if (half == 1 && l < 16) {
            int q  = l >> 2;
            int dy = (l >> 1) & 1, dx = l & 1;
            float a = 0.f;
            #pragma unroll
            for (int kp = 0; kp < 9; ++kp) {
                int ky = kp / 3, kx = kp - 3 * ky;
                const float* spf = &s1f[im][dy + ky][2 * q + dx + kx][0];
                #pragma unroll
                for (int ic = 0; ic < 8; ++ic)
                    a += spf[ic] * c2w[ic * 9 + kp];   // uniform -> s_load
            }
            float m1 = fmaxf(a, __shfl_xor(a, 1));
            float m2 = fmaxf(m1, __shfl_xor(m1, 2));
            if ((l & 3) == 0) exact4[im][q] = fmaxf(m2 + c2b[0], 0.f);
        }
    }
    __syncthreads();

    // ---- bf16 flat write, rows padded to 800
    for (int i = tid; i < 2 * 400; i += 256) {
        int im = i / 400;
        int j  = (i - im * 400) * 2;
        const float* s2i = &sx[im][0];
        float v0 = (j     < 784) ? s2i[j]     : 0.f;
        float v1 = (j + 1 < 784) ? s2i[j + 1] : 0.f;
        unsigned pk = (unsigned)f2bf(v0) | ((unsigned)f2bf(v1) << 16);
        *(unsigned*)(flatb + (size_t)(img0 + im) * 800 + j) = pk;
    }

    // ---- tiny heads (fp32 exact via exact4): one path per wave
    {
        const int wv   = __builtin_amdgcn_readfirstlane(tid >> 6);
        const int lane = tid & 63;
        const int off_samp = bsz * 4;
        const int off_reg  = bsz * 6;
        const int off_ker  = bsz * 7;
        if (wv < 2) {                       // RBF kernel row, im = wv
            if (lane < 10) {
                const int gimg = img0 + wv;
                float f0 = exact4[wv][0], f1 = exact4[wv][1];
                float f2 = exact4[wv][2], f3 = exact4[wv][3];
                float m0 = mem[lane * 4 + 0], m1 = mem[lane * 4 + 1];
                float m2 = mem[lane * 4 + 2], m3 = mem[lane * 4 + 3];
                float sq = f0 * f0 + f1 * f1 + f2 * f2 + f3 * f3
                         + m0 * m0 + m1 * m1 + m2 * m2 + m3 * m3
                         - 2.f * (f0 * m0 + f1 * m1 + f2 * m2 + f3 * m3);
                out[off_ker + (size_t)gimg * 10 + lane] = expf(-sq);
            }
        } else if (wv == 2) {               // sampler, im = lane
            if (lane < 2) {
                const int gimg = img0 + lane;
                float f0 = exact4[lane][0], f1 = exact4[lane][1];
                float t1[4];
                #pragma unroll
                for (int j = 0; j < 4; ++j)
                    t1[j] = tanhf(f0 * sw1[j * 2] + f1 * sw1[j * 2 + 1] + sb1[j]);
                float s0 = sb2[0], s1v = sb2[1];
                #pragma unroll
                for (int j = 0; j < 4; ++j) { s0 += t1[j] * sw2[j]; s1v += t1[j] * sw2[4 + j]; }
                float mx = fmaxf(s0, s1v);
                float e0 = expf(s0 - mx), e1 = expf(s1v - mx);
                float inv = 1.f / (e0 + e1);
                out[off_samp + (size_t)gimg * 2 + 0] = e0 * inv;
                out[off_samp + (size_t)gimg * 2 + 1] = e1 * inv;
            }
        } else {                            // estimator, im = lane
            if (lane < 2) {
                const int gimg = img0 + lane;
                float f0 = exact4[lane][0], f1 = exact4[lane][1];
                float e1a[8];
                #pragma unroll
                for (int j = 0; j < 8; ++j)
                    e1a[j] = tanhf(f0 * ew1[j * 2] + f1 * ew1[j * 2 + 1] + eb1[j]);
                float rg = eb3[0];
                #pragma unroll
                for (int m = 0; m < 4; ++m) {
                    float a = eb2[m];
                    #pragma unroll
                    for (int j = 0; j < 8; ++j) a += e1a[j] * ew2[m * 8 + j];
                    rg += tanhf(a) * ew3[m];
                }
                out[off_reg + gimg] = rg;
            }
        }
    }
}

// ---------------------------------------------------------------------------
// Kernel 3: fc1 (MFMA bf16, M=bsz N=64 K=800) + relu + fc2 fused -> fct[4][bsz]
// ---------------------------------------------------------------------------
__global__ __launch_bounds__(128) void k_fc(
    const unsigned short* __restrict__ flatb, const unsigned short* __restrict__ Bp,
    const float* __restrict__ fc1b, const float* __restrict__ fc2w,
    const float* __restrict__ fc2b, float* __restrict__ fct, int bsz)
{
    __shared__ float h[2][16][68];

    const int tid  = threadIdx.x;
    const int w    = __builtin_amdgcn_readfirstlane(tid >> 6);
    const int l    = tid & 63;
    const int img0 = blockIdx.x * 32 + w * 16;
    const int m15  = l & 15;
    const int grp  = l >> 4;

    const unsigned short* aptr = flatb + (size_t)(img0 + m15) * 800 + grp * 8;
    const unsigned short* bptr = Bp + (size_t)l * 8;

    f32x4 acc[4] = {};
    for (int kb = 0; kb < 25; ++kb) {
        bf16x8 a = *(const bf16x8*)(aptr + kb * 32);
        #pragma unroll
        for (int nf = 0; nf < 4; ++nf) {
            bf16x8 b = *(const bf16x8*)(bptr + (size_t)(kb * 4 + nf) * 64 * 8);
            acc[nf] = __builtin_amdgcn_mfma_f32_16x16x32_bf16(a, b, acc[nf], 0, 0, 0);
        }
    }

    #pragma unroll
    for (int nf = 0; nf < 4; ++nf) {
        int j = nf * 16 + m15;
        float bj = fc1b[j];
        #pragma unroll
        for (int r = 0; r < 4; ++r)
            h[w][grp * 4 + r][j] = fmaxf(acc[nf][r] + bj, 0.f);
    }
    __syncthreads();

    {
        int im = m15, ch = grp;
        float a = fc2b[ch];
        const float* hp = &h[w][im][0];
        const float* wp = &fc2w[ch * 64];
        #pragma unroll 8
        for (int o = 0; o < 64; ++o) a += hp[o] * wp[o];
        fct[(size_t)ch * bsz + img0 + im] = a;
    }
}

// ---------------------------------------------------------------------------
// Kernel 4: BN partials — 64 blocks = (channel, segment)
// ---------------------------------------------------------------------------
__global__ __launch_bounds__(256) void k_bnred1(
    const float* __restrict__ fct, float* __restrict__ partial, int bsz)
{
    const int tid = threadIdx.x;
    const int ch  = blockIdx.x & 3;
    const int seg = blockIdx.x >> 2;
    const int n   = bsz / 16;
    const float* p = fct + (size_t)ch * bsz + seg * n;
    float s = 0.f, ss = 0.f;
    for (int i = tid; i < n; i += 256) {
        float v = p[i];
        s += v; ss += v * v;
    }
    __shared__ float rs[256], rss[256];
    rs[tid] = s; rss[tid] = ss;
    __syncthreads();
    for (int off = 128; off >= 1; off >>= 1) {
        if (tid < off) { rs[tid] += rs[tid + off]; rss[tid] += rss[tid + off]; }
        __syncthreads();
    }
    if (tid == 0) {
        partial[blockIdx.x * 2]     = rs[0];
        partial[blockIdx.x * 2 + 1] = rss[0];
    }
}

__global__ __launch_bounds__(64) void k_bnred2(
    const float* __restrict__ partial, const float* __restrict__ g,
    const float* __restrict__ bb, float* __restrict__ bnp, int bsz)
{
    const int tid = threadIdx.x;
    if (tid < 4) {
        float s = 0.f, ss = 0.f;
        for (int seg = 0; seg < 16; ++seg) {
            s  += partial[(seg * 4 + tid) * 2];
            ss += partial[(seg * 4 + tid) * 2 + 1];
        }
        float n = (float)bsz;
        float mu  = s / n;
        float var = ss / n - mu * mu;
        float scale = g[tid] * rsqrtf(var + EPS_BN);
        bnp[tid]     = scale;
        bnp[4 + tid] = bb[tid] - mu * scale;
    }
}

// ---------------------------------------------------------------------------
// Kernel 5: apply BN -> logits, float4 store
// ---------------------------------------------------------------------------
__global__ __launch_bounds__(256) void k_bnapply(
    const float* __restrict__ fct, const float* __restrict__ bnp,
    float* __restrict__ out, int bsz)
{
    const int img = blockIdx.x * 256 + threadIdx.x;
    float4 r;
    r.x = fct[img]           * bnp[0] + bnp[4];
    r.y = fct[bsz + img]     * bnp[1] + bnp[5];
    r.z = fct[2 * bsz + img] * bnp[2] + bnp[6];
    r.w = fct[3 * bsz + img] * bnp[3] + bnp[7];
    *(float4*)(out + (size_t)img * 4) = r;
}

// ---------------------------------------------------------------------------
extern "C" void kernel_launch(void* const* d_in, const int* in_sizes, int n_in,
                              void* d_out, int out_size, void* d_ws, size_t ws_size,
                              hipStream_t stream) {
    const float* x     = (const float*)d_in[0];
    const float* c1w   = (const float*)d_in[1];
    const float* c1b   = (const float*)d_in[2];
    const float* c2w   = (const float*)d_in[3];
    const float* c2b   = (const float*)d_in[4];
    const float* fc1w  = (const float*)d_in[5];
    const float* fc1b  = (const float*)d_in[6];
    const float* fc2w  = (const float*)d_in[7];
    const float* fc2b  = (const float*)d_in[8];
    const float* bng   = (const float*)d_in[9];
    const float* bnb   = (const float*)d_in[10];
    const float* sw1   = (const float*)d_in[11];
    const float* sb1   = (const float*)d_in[12];
    const float* sw2   = (const float*)d_in[13];
    const float* sb2   = (const float*)d_in[14];
    const float* ew1   = (const float*)d_in[15];
    const float* eb1   = (const float*)d_in[16];
    const float* ew2   = (const float*)d_in[17];
    const float* eb2   = (const float*)d_in[18];
    const float* ew3   = (const float*)d_in[19];
    const float* eb3   = (const float*)d_in[20];
    const float* mem   = (const float*)d_in[21];

    const int bsz = in_sizes[0] / 784;         // 8192
    float* out = (float*)d_out;

    unsigned short* flatb = (unsigned short*)d_ws;           // bsz*800 bf16
    unsigned short* Bp    = flatb + (size_t)bsz * 800;       // 51200 bf16
    unsigned short* Bc2   = Bp + 51200;                      // 1536 bf16
    float* fct            = (float*)(Bc2 + 1536);            // 4*bsz
    float* partial        = fct + (size_t)bsz * 4;           // 128
    float* bnp            = partial + 128;                   // 8

    k_prep<<<201, 256, 0, stream>>>(fc1w, c2w, Bp, Bc2);
    k_conv<<<bsz / 2, 256, 0, stream>>>(x, c1w, c1b, c2w, c2b, Bc2,
                                        sw1, sb1, sw2, sb2,
                                        ew1, eb1, ew2, eb2, ew3, eb3, mem,
                                        flatb, out, bsz);
    k_fc<<<bsz / 32, 128, 0, stream>>>(flatb, Bp, fc1b, fc2w, fc2b, fct, bsz);
    k_bnred1<<<64, 256, 0, stream>>>(fct, partial, bsz);
    k_bnred2<<<1, 64, 0, stream>>>(partial, bng, bnb, bnp, bsz);
    k_bnapply<<<bsz / 256, 256, 0, stream>>>(fct, bnp, out, bsz);
}

// Round 8
// 62.643 us; speedup vs baseline: 2.6552x; 1.0026x over previous
//
#include <hip/hip_runtime.h>
#include <math.h>

#define EPS_BN 1e-5f

typedef float  f32x4  __attribute__((ext_vector_type(4)));
typedef short  bf16x8 __attribute__((ext_vector_type(8)));

__device__ inline unsigned short f2bf(float f) {
    union { float f; unsigned u; } c; c.f = f;
    unsigned u = c.u;
    return (unsigned short)((u + 0x7FFFu + ((u >> 16) & 1u)) >> 16);  // RNE
}
__device__ inline void pinf(float& x)    { asm volatile("" : "+v"(x)); }
__device__ inline void pinu(unsigned& x) { asm volatile("" : "+v"(x)); }

// ---------------------------------------------------------------------------
// Kernel 1: weight packs (fc1_w -> Bp frag; conv2_w -> Bc2 frag)
// ---------------------------------------------------------------------------
__global__ __launch_bounds__(256) void k_prep(const float* __restrict__ fc1w,
                                              const float* __restrict__ c2w,
                                              unsigned short* __restrict__ Bp,
                                              unsigned short* __restrict__ Bc2) {
    if (blockIdx.x < 200) {
        int t = blockIdx.x * 256 + threadIdx.x;   // < 51200
        int j  = t & 7;
        int l  = (t >> 3) & 63;
        int nf = (t >> 9) & 3;
        int kb = t >> 11;
        int k  = kb * 32 + (l >> 4) * 8 + j;
        int o  = nf * 16 + (l & 15);
        float v = (k < 784) ? fc1w[o * 784 + k] : 0.f;
        Bp[t] = f2bf(v);
    } else {
        for (int t = threadIdx.x; t < 1536; t += 256) {
            int j  = t & 7;            // ic
            int l  = (t >> 3) & 63;
            int g  = t >> 9;           // k-group
            int kp = 4 * g + (l >> 4); // kernel position
            int oc = l & 15;
            float v = (kp < 9) ? c2w[(oc * 8 + j) * 9 + kp] : 0.f;
            Bc2[t] = f2bf(v);
        }
    }
}

// ---------------------------------------------------------------------------
// Kernel 2: conv1(vector) + conv2(MFMA) + bf16 flat + exact4 — 2 img/block
// ---------------------------------------------------------------------------
__global__ __launch_bounds__(256, 6) void k_conv(
    const float* __restrict__ x,
    const float* __restrict__ c1w, const float* __restrict__ c1b,
    const float* __restrict__ c2w, const float* __restrict__ c2b,
    const unsigned short* __restrict__ Bc2,
    unsigned short* __restrict__ flatb, float* __restrict__ exact4g, int bsz)
{
    __shared__ float sx[2][900];                          // 30x30 halo input; later flat
    __shared__ __align__(16) unsigned short s1t[2][16][16][8]; // bf16 conv1 out, halo
    __shared__ float s1f[2][4][12][8];                    // f32 corner for exact heads

    const int tid  = threadIdx.x;
    const int img0 = blockIdx.x * 2;

    // ---- zero input halo
    if (tid < 232) {
        int im = tid / 116;
        int r  = tid - im * 116;
        int idx;
        if      (r < 30) idx = r;
        else if (r < 60) idx = 29 * 30 + (r - 30);
        else if (r < 88) idx = (r - 60 + 1) * 30;
        else             idx = (r - 88 + 1) * 30 + 29;
        sx[im][idx] = 0.f;
    }
    // ---- stage interior
    const float* xb = x + (size_t)img0 * 784;
    for (int i = tid; i < 1568; i += 256) {
        int im = i / 784;
        int j  = i - im * 784;
        sx[im][(j / 28 + 1) * 30 + (j % 28) + 1] = xb[i];
    }
    // ---- zero s1t halo
    for (int q = tid; q < 120; q += 256) {
        int im = q / 60, r = q - im * 60;
        int Y, X;
        if      (r < 16) { Y = 0;          X = r; }
        else if (r < 32) { Y = 15;         X = r - 16; }
        else if (r < 46) { Y = r - 32 + 1; X = 0; }
        else             { Y = r - 46 + 1; X = 15; }
        *(uint4*)&s1t[im][Y][X][0] = make_uint4(0, 0, 0, 0);
    }
    // ---- zero s1f
    for (int q = tid; q < 192; q += 256) ((float4*)s1f)[q] = make_float4(0, 0, 0, 0);
    __syncthreads();

    // ---- conv1 (1->8) + relu + pool: 196 tasks = (img, py, px-pair)
    if (tid < 196) {
        int im  = tid / 98;
        int r   = tid - im * 98;
        int py  = r / 7;
        int pxq = r - py * 7;
        const float* sp = &sx[im][(2 * py) * 30 + 4 * pxq];
        float win[4][6];
        #pragma unroll
        for (int wy = 0; wy < 4; ++wy) {
            #pragma unroll
            for (int t = 0; t < 3; ++t) {
                float2 v = *(const float2*)(sp + wy * 30 + 2 * t);
                win[wy][2 * t]     = v.x;
                win[wy][2 * t + 1] = v.y;
            }
        }
        // pin window in VGPRs so the channel loop reuses instead of re-reading LDS
        #pragma unroll
        for (int wy = 0; wy < 4; ++wy)
            #pragma unroll
            for (int wx = 0; wx < 6; ++wx) pinf(win[wy][wx]);

        unsigned pk0[4] = {0, 0, 0, 0}, pk1[4] = {0, 0, 0, 0};
        const bool sf = (py <= 2) && (pxq <= 4);
        #pragma unroll
        for (int c = 0; c < 8; ++c) {
            const float* wp = &c1w[c * 9];            // uniform -> s_load
            float bb = c1b[c];
            float a[2][2][2];
            #pragma unroll
            for (int q = 0; q < 2; ++q)
                #pragma unroll
                for (int dy = 0; dy < 2; ++dy)
                    #pragma unroll
                    for (int dx = 0; dx < 2; ++dx) a[q][dy][dx] = bb;
            #pragma unroll
            for (int ky = 0; ky < 3; ++ky) {
                #pragma unroll
                for (int kx = 0; kx < 3; ++kx) {
                    float wv = wp[ky * 3 + kx];
                    #pragma unroll
                    for (int q = 0; q < 2; ++q)
                        #pragma unroll
                        for (int dy = 0; dy < 2; ++dy)
                            #pragma unroll
                            for (int dx = 0; dx < 2; ++dx)
                                a[q][dy][dx] += win[dy + ky][2 * q + dx + kx] * wv;
                }
            }
            float v0 = fmaxf(fmaxf(fmaxf(a[0][0][0], a[0][0][1]),
                                   fmaxf(a[0][1][0], a[0][1][1])), 0.f);
            float v1 = fmaxf(fmaxf(fmaxf(a[1][0][0], a[1][0][1]),
                                   fmaxf(a[1][1][0], a[1][1][1])), 0.f);
            pk0[c >> 1] |= (unsigned)f2bf(v0) << ((c & 1) * 16);
            pk1[c >> 1] |= (unsigned)f2bf(v1) << ((c & 1) * 16);
            if (sf) {
                s1f[im][py + 1][2 * pxq + 1][c] = v0;
                s1f[im][py + 1][2 * pxq + 2][c] = v1;
            }
        }
        *(uint4*)&s1t[im][py + 1][2 * pxq + 1][0] = make_uint4(pk0[0], pk0[1], pk0[2], pk0[3]);
        *(uint4*)&s1t[im][py + 1][2 * pxq + 2][0] = make_uint4(pk1[0], pk1[1], pk1[2], pk1[3]);
    }
    __syncthreads();

    // ---- conv2 (8->16) + relu + pool via MFMA, quad-major M ordering
    {
        const int wv   = __builtin_amdgcn_readfirstlane(tid >> 6);
        const int im   = wv >> 1;
        const int half = wv & 1;
        const int l    = tid & 63;
        const int grp  = l >> 4;
        const int m15  = l & 15;

        union { uint4 u; bf16x8 v; } bfr[3];
        #pragma unroll
        for (int g = 0; g < 3; ++g) {
            bfr[g].u = *(const uint4*)(Bc2 + (size_t)(g * 64 + l) * 8);
            pinu(bfr[g].u.x); pinu(bfr[g].u.y); pinu(bfr[g].u.z); pinu(bfr[g].u.w);
        }

        int koff[3];
        #pragma unroll
        for (int g = 0; g < 3; ++g) {
            int kp = 4 * g + grp;
            koff[g] = (kp < 9) ? ((kp / 3) * 16 + (kp % 3)) * 8 : 0;
        }
        const float bias = c2b[m15];
        float* s2i = &sx[im][0];                 // input dead -> flat row

        for (int t = half; t < 13; t += 2) {
            int qa = 4 * t + (m15 >> 2);
            if (qa > 48) qa = 48;                // pad rows replicate row q=48
            int s  = m15 & 3;
            int py = qa / 7, px = qa - 7 * py;
            int y  = 2 * py + (s >> 1), xx = 2 * px + (s & 1);
            const unsigned short* ab = &s1t[im][y][xx][0];
            f32x4 acc = {};
            #pragma unroll
            for (int g = 0; g < 3; ++g) {
                bf16x8 a = *(const bf16x8*)(ab + koff[g]);
                acc = __builtin_amdgcn_mfma_f32_16x16x32_bf16(a, bfr[g].v, acc, 0, 0, 0);
            }
            float m = fmaxf(fmaxf(acc[0], acc[1]), fmaxf(acc[2], acc[3]));
            float val = fmaxf(m + bias, 0.f);
            int qo = 4 * t + grp;                // lane's output quad
            if (qo < 49) s2i[m15 * 49 + qo] = val;
        }

        // ---- exact fp32 flat[:4] (ch 0, quads 0..3) on waves 1,3 lanes 0..15
        if (half == 1 && l < 16) {
            int q  = l >> 2;
            int dy = (l >> 1) & 1, dx = l & 1;
            float a = 0.f;
            #pragma unroll
            for (int kp = 0; kp < 9; ++kp) {
                int ky = kp / 3, kx = kp - 3 * ky;
                const float* spf = &s1f[im][dy + ky][2 * q + dx + kx][0];
                #pragma unroll
                for (int ic = 0; ic < 8; ++ic)
                    a += spf[ic] * c2w[ic * 9 + kp];   // uniform -> s_load
            }
            float m1 = fmaxf(a, __shfl_xor(a, 1));
            float m2 = fmaxf(m1, __shfl_xor(m1, 2));
            if ((l & 3) == 0)
                exact4g[(size_t)(img0 + im) * 4 + q] = fmaxf(m2 + c2b[0], 0.f);
        }
    }
    __syncthreads();

    // ---- bf16 flat write, rows padded to 800
    for (int i = tid; i < 2 * 400; i += 256) {
        int im = i / 400;
        int j  = (i - im * 400) * 2;
        const float* s2i = &sx[im][0];
        float v0 = (j     < 784) ? s2i[j]     : 0.f;
        float v1 = (j + 1 < 784) ? s2i[j + 1] : 0.f;
        unsigned pk = (unsigned)f2bf(v0) | ((unsigned)f2bf(v1) << 16);
        *(unsigned*)(flatb + (size_t)(img0 + im) * 800 + j) = pk;
    }
}

// ---------------------------------------------------------------------------
// Kernel 3: tiny heads (fp32 exact), 1 thread = 1 image
// ---------------------------------------------------------------------------
__global__ __launch_bounds__(256) void k_heads(
    const float* __restrict__ exact4g,
    const float* __restrict__ sw1, const float* __restrict__ sb1,
    const float* __restrict__ sw2, const float* __restrict__ sb2,
    const float* __restrict__ ew1, const float* __restrict__ eb1,
    const float* __restrict__ ew2, const float* __restrict__ eb2,
    const float* __restrict__ ew3, const float* __restrict__ eb3,
    const float* __restrict__ mem,
    float* __restrict__ out, int bsz)
{
    const int img = blockIdx.x * 256 + threadIdx.x;
    const float4 f = *(const float4*)(exact4g + (size_t)img * 4);
    const float f0 = f.x, f1 = f.y, f2 = f.z, f3 = f.w;
    const int off_samp = bsz * 4;
    const int off_reg  = bsz * 6;
    const int off_ker  = bsz * 7;

    // RBF kernel row
    float qq = f0 * f0 + f1 * f1 + f2 * f2 + f3 * f3;
    #pragma unroll
    for (int j = 0; j < 10; ++j) {
        float m0 = mem[j * 4 + 0], m1 = mem[j * 4 + 1];
        float m2 = mem[j * 4 + 2], m3 = mem[j * 4 + 3];
        float sq = qq + m0 * m0 + m1 * m1 + m2 * m2 + m3 * m3
                 - 2.f * (f0 * m0 + f1 * m1 + f2 * m2 + f3 * m3);
        out[off_ker + (size_t)img * 10 + j] = expf(-sq);
    }
    // sampler
    {
        float t1[4];
        #pragma unroll
        for (int j = 0; j < 4; ++j)
            t1[j] = tanhf(f0 * sw1[j * 2] + f1 * sw1[j * 2 + 1] + sb1[j]);
        float s0 = sb2[0], s1v = sb2[1];
        #pragma unroll
        for (int j = 0; j < 4; ++j) { s0 += t1[j] * sw2[j]; s1v += t1[j] * sw2[4 + j]; }
        float mx = fmaxf(s0, s1v);
        float e0 = expf(s0 - mx), e1 = expf(s1v - mx);
        float inv = 1.f / (e0 + e1);
        out[off_samp + (size_t)img * 2 + 0] = e0 * inv;
        out[off_samp + (size_t)img * 2 + 1] = e1 * inv;
    }
    // estimator
    {
        float e1a[8];
        #pragma unroll
        for (int j = 0; j < 8; ++j)
            e1a[j] = tanhf(f0 * ew1[j * 2] + f1 * ew1[j * 2 + 1] + eb1[j]);
        float rg = eb3[0];
        #pragma unroll
        for (int m = 0; m < 4; ++m) {
            float a = eb2[m];
            #pragma unroll
            for (int j = 0; j < 8; ++j) a += e1a[j] * ew2[m * 8 + j];
            rg += tanhf(a) * ew3[m];
        }
        out[off_reg + img] = rg;
    }
}

// ---------------------------------------------------------------------------
// Kernel 4: fc1 (MFMA bf16, M=bsz N=64 K=800) + relu + fc2 fused -> fct[4][bsz]
// ---------------------------------------------------------------------------
__global__ __launch_bounds__(128) void k_fc(
    const unsigned short* __restrict__ flatb, const unsigned short* __restrict__ Bp,
    const float* __restrict__ fc1b, const float* __restrict__ fc2w,
    const float* __restrict__ fc2b, float* __restrict__ fct, int bsz)
{
    __shared__ float h[2][16][68];

    const int tid  = threadIdx.x;
    const int w    = __builtin_amdgcn_readfirstlane(tid >> 6);
    const int l    = tid & 63;
    const int img0 = blockIdx.x * 32 + w * 16;
    const int m15  = l & 15;
    const int grp  = l >> 4;

    const unsigned short* aptr = flatb + (size_t)(img0 + m15) * 800 + grp * 8;
    const unsigned short* bptr = Bp + (size_t)l * 8;

    f32x4 acc[4] = {};
    for (int kb = 0; kb < 25; ++kb) {
        bf16x8 a = *(const bf16x8*)(aptr + kb * 32);
        #pragma unroll
        for (int nf = 0; nf < 4; ++nf) {
            bf16x8 b = *(const bf16x8*)(bptr + (size_t)(kb * 4 + nf) * 64 * 8);
            acc[nf] = __builtin_amdgcn_mfma_f32_16x16x32_bf16(a, b, acc[nf], 0, 0, 0);
        }
    }

    #pragma unroll
    for (int nf = 0; nf < 4; ++nf) {
        int j = nf * 16 + m15;
        float bj = fc1b[j];
        #pragma unroll
        for (int r = 0; r < 4; ++r)
            h[w][grp * 4 + r][j] = fmaxf(acc[nf][r] + bj, 0.f);
    }
    __syncthreads();

    {
        int im = m15, ch = grp;
        float a = fc2b[ch];
        const float* hp = &h[w][im][0];
        const float* wp = &fc2w[ch * 64];
        #pragma unroll 8
        for (int o = 0; o < 64; ++o) a += hp[o] * wp[o];
        fct[(size_t)ch * bsz + img0 + im] = a;
    }
}

// ---------------------------------------------------------------------------
// Kernel 5: BN partials — 64 blocks = (channel, segment)
// ---------------------------------------------------------------------------
__global__ __launch_bounds__(256) void k_bnred1(
    const float* __restrict__ fct, float* __restrict__ partial, int bsz)
{
    const int tid = threadIdx.x;
    const int ch  = blockIdx.x & 3;
    const int seg = blockIdx.x >> 2;
    const int n   = bsz / 16;
    const float* p = fct + (size_t)ch * bsz + seg * n;
    float s = 0.f, ss = 0.f;
    for (int i = tid; i < n; i += 256) {
        float v = p[i];
        s += v; ss += v * v;
    }
    __shared__ float rs[256], rss[256];
    rs[tid] = s; rss[tid] = ss;
    __syncthreads();
    for (int off = 128; off >= 1; off >>= 1) {
        if (tid < off) { rs[tid] += rs[tid + off]; rss[tid] += rss[tid + off]; }
        __syncthreads();
    }
    if (tid == 0) {
        partial[blockIdx.x * 2]     = rs[0];
        partial[blockIdx.x * 2 + 1] = rss[0];
    }
}

__global__ __launch_bounds__(64) void k_bnred2(
    const float* __restrict__ partial, const float* __restrict__ g,
    const float* __restrict__ bb, float* __restrict__ bnp, int bsz)
{
    const int tid = threadIdx.x;
    if (tid < 4) {
        float s = 0.f, ss = 0.f;
        for (int seg = 0; seg < 16; ++seg) {
            s  += partial[(seg * 4 + tid) * 2];
            ss += partial[(seg * 4 + tid) * 2 + 1];
        }
        float n = (float)bsz;
        float mu  = s / n;
        float var = ss / n - mu * mu;
        float scale = g[tid] * rsqrtf(var + EPS_BN);
        bnp[tid]     = scale;
        bnp[4 + tid] = bb[tid] - mu * scale;
    }
}

// ---------------------------------------------------------------------------
// Kernel 6: apply BN -> logits, float4 store
// ---------------------------------------------------------------------------
__global__ __launch_bounds__(256) void k_bnapply(
    const float* __restrict__ fct, const float* __restrict__ bnp,
    float* __restrict__ out, int bsz)
{
    const int img = blockIdx.x * 256 + threadIdx.x;
    float4 r;
    r.x = fct[img]           * bnp[0] + bnp[4];
    r.y = fct[bsz + img]     * bnp[1] + bnp[5];
    r.z = fct[2 * bsz + img] * bnp[2] + bnp[6];
    r.w = fct[3 * bsz + img] * bnp[3] + bnp[7];
    *(float4*)(out + (size_t)img * 4) = r;
}

// ---------------------------------------------------------------------------
extern "C" void kernel_launch(void* const* d_in, const int* in_sizes, int n_in,
                              void* d_out, int out_size, void* d_ws, size_t ws_size,
                              hipStream_t stream) {
    const float* x     = (const float*)d_in[0];
    const float* c1w   = (const float*)d_in[1];
    const float* c1b   = (const float*)d_in[2];
    const float* c2w   = (const float*)d_in[3];
    const float* c2b   = (const float*)d_in[4];
    const float* fc1w  = (const float*)d_in[5];
    const float* fc1b  = (const float*)d_in[6];
    const float* fc2w  = (const float*)d_in[7];
    const float* fc2b  = (const float*)d_in[8];
    const float* bng   = (const float*)d_in[9];
    const float* bnb   = (const float*)d_in[10];
    const float* sw1   = (const float*)d_in[11];
    const float* sb1   = (const float*)d_in[12];
    const float* sw2   = (const float*)d_in[13];
    const float* sb2   = (const float*)d_in[14];
    const float* ew1   = (const float*)d_in[15];
    const float* eb1   = (const float*)d_in[16];
    const float* ew2   = (const float*)d_in[17];
    const float* eb2   = (const float*)d_in[18];
    const float* ew3   = (const float*)d_in[19];
    const float* eb3   = (const float*)d_in[20];
    const float* mem   = (const float*)d_in[21];

    const int bsz = in_sizes[0] / 784;         // 8192
    float* out = (float*)d_out;

    unsigned short* flatb = (unsigned short*)d_ws;           // bsz*800 bf16
    unsigned short* Bp    = flatb + (size_t)bsz * 800;       // 51200 bf16
    unsigned short* Bc2   = Bp + 51200;                      // 1536 bf16
    float* fct            = (float*)(Bc2 + 1536);            // 4*bsz
    float* partial        = fct + (size_t)bsz * 4;           // 128
    float* bnp            = partial + 128;                   // 8
    float* exact4g        = bnp + 8;                         // 4*bsz

    k_prep<<<201, 256, 0, stream>>>(fc1w, c2w, Bp, Bc2);
    k_conv<<<bsz / 2, 256, 0, stream>>>(x, c1w, c1b, c2w, c2b, Bc2,
                                        flatb, exact4g, bsz);
    k_heads<<<bsz / 256, 256, 0, stream>>>(exact4g, sw1, sb1, sw2, sb2,
                                           ew1, eb1, ew2, eb2, ew3, eb3, mem,
                                           out, bsz);
    k_fc<<<bsz / 32, 128, 0, stream>>>(flatb, Bp, fc1b, fc2w, fc2b, fct, bsz);
    k_bnred1<<<64, 256, 0, stream>>>(fct, partial, bsz);
    k_bnred2<<<1, 64, 0, stream>>>(partial, bng, bnb, bnp, bsz);
    k_bnapply<<<bsz / 256, 256, 0, stream>>>(fct, bnp, out, bsz);
}

// Round 9
// 56.535 us; speedup vs baseline: 2.9421x; 1.1080x over previous
//
#include <hip/hip_runtime.h>
#include <math.h>

#define EPS_BN 1e-5f

typedef float  f32x4  __attribute__((ext_vector_type(4)));
typedef float  f32x2  __attribute__((ext_vector_type(2)));
typedef short  bf16x8 __attribute__((ext_vector_type(8)));

__device__ inline unsigned short f2bf(float f) {
    union { float f; unsigned u; } c; c.f = f;
    unsigned u = c.u;
    return (unsigned short)((u + 0x7FFFu + ((u >> 16) & 1u)) >> 16);  // RNE
}

// ---------------------------------------------------------------------------
// Kernel 1: weight packs (fc1_w -> Bp frag; conv2_w -> Bc2 frag)
// ---------------------------------------------------------------------------
__global__ __launch_bounds__(256) void k_prep(const float* __restrict__ fc1w,
                                              const float* __restrict__ c2w,
                                              unsigned short* __restrict__ Bp,
                                              unsigned short* __restrict__ Bc2) {
    if (blockIdx.x < 200) {
        int t = blockIdx.x * 256 + threadIdx.x;   // < 51200
        int j  = t & 7;
        int l  = (t >> 3) & 63;
        int nf = (t >> 9) & 3;
        int kb = t >> 11;
        int k  = kb * 32 + (l >> 4) * 8 + j;
        int o  = nf * 16 + (l & 15);
        float v = (k < 784) ? fc1w[o * 784 + k] : 0.f;
        Bp[t] = f2bf(v);
    } else {
        for (int t = threadIdx.x; t < 1536; t += 256) {
            int j  = t & 7;            // ic
            int l  = (t >> 3) & 63;
            int g  = t >> 9;           // k-group
            int kp = 4 * g + (l >> 4); // kernel position
            int oc = l & 15;
            float v = (kp < 9) ? c2w[(oc * 8 + j) * 9 + kp] : 0.f;
            Bc2[t] = f2bf(v);
        }
    }
}

// ---------------------------------------------------------------------------
// Kernel 2: conv1(pk_fma) + conv2(MFMA) + bf16 flat + exact4 — 2 img/block
// ---------------------------------------------------------------------------
__global__ __launch_bounds__(256, 4) void k_conv(
    const float* __restrict__ x,
    const float* __restrict__ c1w, const float* __restrict__ c1b,
    const float* __restrict__ c2w, const float* __restrict__ c2b,
    const unsigned short* __restrict__ Bc2,
    unsigned short* __restrict__ flatb, float* __restrict__ exact4g, int bsz)
{
    __shared__ float sx[2][900];                          // 30x30 halo input; later flat(bf16)
    __shared__ __align__(16) unsigned short s1t[2][16][16][8]; // bf16 conv1 out, halo
    __shared__ float s1f[2][4][12][8];                    // f32 corner for exact heads

    const int tid  = threadIdx.x;
    const int img0 = blockIdx.x * 2;

    // ---- zero input halo
    if (tid < 232) {
        int im = tid / 116;
        int r  = tid - im * 116;
        int idx;
        if      (r < 30) idx = r;
        else if (r < 60) idx = 29 * 30 + (r - 30);
        else if (r < 88) idx = (r - 60 + 1) * 30;
        else             idx = (r - 88 + 1) * 30 + 29;
        sx[im][idx] = 0.f;
    }
    // ---- stage interior
    const float* xb = x + (size_t)img0 * 784;
    for (int i = tid; i < 1568; i += 256) {
        int im = i / 784;
        int j  = i - im * 784;
        sx[im][(j / 28 + 1) * 30 + (j % 28) + 1] = xb[i];
    }
    // ---- zero s1t halo
    for (int q = tid; q < 120; q += 256) {
        int im = q / 60, r = q - im * 60;
        int Y, X;
        if      (r < 16) { Y = 0;          X = r; }
        else if (r < 32) { Y = 15;         X = r - 16; }
        else if (r < 46) { Y = r - 32 + 1; X = 0; }
        else             { Y = r - 46 + 1; X = 15; }
        *(uint4*)&s1t[im][Y][X][0] = make_uint4(0, 0, 0, 0);
    }
    // ---- zero s1f
    for (int q = tid; q < 192; q += 256) ((float4*)s1f)[q] = make_float4(0, 0, 0, 0);
    __syncthreads();

    // ---- conv1 (1->8) + relu + pool via v_pk_fma_f32: 196 tasks = (img,py,pxq)
    if (tid < 196) {
        int im  = tid / 98;
        int r   = tid - im * 98;
        int py  = r / 7;
        int pxq = r - py * 7;
        const float* sp = &sx[im][(2 * py) * 30 + 4 * pxq];  // 8B-aligned base
        // rows: 3 aligned pairs r[wy][0..2] = (w0,w1)(w2,w3)(w4,w5), 2 shifted
        f32x2 rp[4][3], sh[4][2];
        #pragma unroll
        for (int wy = 0; wy < 4; ++wy) {
            rp[wy][0] = *(const f32x2*)(sp + wy * 30);
            rp[wy][1] = *(const f32x2*)(sp + wy * 30 + 2);
            rp[wy][2] = *(const f32x2*)(sp + wy * 30 + 4);
            sh[wy][0] = (f32x2){rp[wy][0].y, rp[wy][1].x};   // (w1,w2)
            sh[wy][1] = (f32x2){rp[wy][1].y, rp[wy][2].x};   // (w3,w4)
        }
        unsigned pk0[4] = {0, 0, 0, 0}, pk1[4] = {0, 0, 0, 0};
        const bool sf = (py <= 2) && (pxq <= 4);
        #pragma unroll
        for (int c = 0; c < 8; ++c) {
            const float* wp = &c1w[c * 9];            // uniform -> s_load
            float bb = c1b[c];
            f32x2 A[2][2];                             // [q][dy], lanes = dx
            A[0][0] = (f32x2){bb, bb}; A[0][1] = (f32x2){bb, bb};
            A[1][0] = (f32x2){bb, bb}; A[1][1] = (f32x2){bb, bb};
            #pragma unroll
            for (int ky = 0; ky < 3; ++ky) {
                #pragma unroll
                for (int kx = 0; kx < 3; ++kx) {
                    float wv = wp[ky * 3 + kx];
                    f32x2 wv2 = (f32x2){wv, wv};
                    #pragma unroll
                    for (int dy = 0; dy < 2; ++dy) {
                        int row = dy + ky;
                        f32x2 s0 = (kx == 0) ? rp[row][0] : (kx == 1) ? sh[row][0] : rp[row][1];
                        f32x2 s1v = (kx == 0) ? rp[row][1] : (kx == 1) ? sh[row][1] : rp[row][2];
                        A[0][dy] = __builtin_elementwise_fma(s0,  wv2, A[0][dy]);
                        A[1][dy] = __builtin_elementwise_fma(s1v, wv2, A[1][dy]);
                    }
                }
            }
            f32x2 m0 = __builtin_elementwise_max(A[0][0], A[0][1]);
            f32x2 m1 = __builtin_elementwise_max(A[1][0], A[1][1]);
            float v0 = fmaxf(fmaxf(m0.x, m0.y), 0.f);
            float v1 = fmaxf(fmaxf(m1.x, m1.y), 0.f);
            pk0[c >> 1] |= (unsigned)f2bf(v0) << ((c & 1) * 16);
            pk1[c >> 1] |= (unsigned)f2bf(v1) << ((c & 1) * 16);
            if (sf) {
                s1f[im][py + 1][2 * pxq + 1][c] = v0;
                s1f[im][py + 1][2 * pxq + 2][c] = v1;
            }
        }
        *(uint4*)&s1t[im][py + 1][2 * pxq + 1][0] = make_uint4(pk0[0], pk0[1], pk0[2], pk0[3]);
        *(uint4*)&s1t[im][py + 1][2 * pxq + 2][0] = make_uint4(pk1[0], pk1[1], pk1[2], pk1[3]);
    }
    __syncthreads();

    // ---- conv2 (8->16) + relu + pool via MFMA, quad-major M ordering
    {
        const int wv   = __builtin_amdgcn_readfirstlane(tid >> 6);
        const int im   = wv >> 1;
        const int half = wv & 1;
        const int l    = tid & 63;
        const int grp  = l >> 4;
        const int m15  = l & 15;

        bf16x8 bfr[3];
        #pragma unroll
        for (int g = 0; g < 3; ++g)
            bfr[g] = *(const bf16x8*)(Bc2 + (size_t)(g * 64 + l) * 8);

        int koff[3];
        #pragma unroll
        for (int g = 0; g < 3; ++g) {
            int kp = 4 * g + grp;
            koff[g] = (kp < 9) ? ((kp / 3) * 16 + (kp % 3)) * 8 : 0;
        }
        const float bias = c2b[m15];
        unsigned short* s2b = (unsigned short*)&sx[im][0];   // input dead -> bf16 flat

        for (int t = half; t < 13; t += 2) {
            int qa = 4 * t + (m15 >> 2);
            if (qa > 48) qa = 48;                // pad rows replicate row q=48
            int s  = m15 & 3;
            int py = qa / 7, px = qa - 7 * py;
            int y  = 2 * py + (s >> 1), xx = 2 * px + (s & 1);
            const unsigned short* ab = &s1t[im][y][xx][0];
            f32x4 acc = {};
            #pragma unroll
            for (int g = 0; g < 3; ++g) {
                bf16x8 a = *(const bf16x8*)(ab + koff[g]);
                acc = __builtin_amdgcn_mfma_f32_16x16x32_bf16(a, bfr[g], acc, 0, 0, 0);
            }
            float m = fmaxf(fmaxf(acc[0], acc[1]), fmaxf(acc[2], acc[3]));
            float val = fmaxf(m + bias, 0.f);
            int qo = 4 * t + grp;                // lane's output quad
            if (qo < 49) s2b[m15 * 49 + qo] = f2bf(val);
        }

        // ---- exact fp32 flat[:4] (ch 0, quads 0..3) on waves 1,3 lanes 0..15
        if (half == 1 && l < 16) {
            int q  = l >> 2;
            int dy = (l >> 1) & 1, dx = l & 1;
            float a = 0.f;
            #pragma unroll
            for (int kp = 0; kp < 9; ++kp) {
                int ky = kp / 3, kx = kp - 3 * ky;
                const float* spf = &s1f[im][dy + ky][2 * q + dx + kx][0];
                #pragma unroll
                for (int ic = 0; ic < 8; ++ic)
                    a += spf[ic] * c2w[ic * 9 + kp];   // uniform -> s_load
            }
            float m1 = fmaxf(a, __shfl_xor(a, 1));
            float m2 = fmaxf(m1, __shfl_xor(m1, 2));
            if ((l & 3) == 0)
                exact4g[(size_t)(img0 + im) * 4 + q] = fmaxf(m2 + c2b[0], 0.f);
        }
    }
    __syncthreads();

    // ---- flat copy LDS(bf16) -> global, rows padded to 800 (u32 = 2 vals)
    for (int i = tid; i < 2 * 400; i += 256) {
        int im = i / 400;
        int j  = i - im * 400;                    // u32 index within row
        const unsigned short* s2b = (const unsigned short*)&sx[im][0];
        unsigned pk = (j < 392) ? *(const unsigned*)(s2b + 2 * j) : 0u;
        *(unsigned*)(flatb + (size_t)(img0 + im) * 800 + 2 * j) = pk;
    }
}

// ---------------------------------------------------------------------------
// Kernel 3: tiny heads (fp32 exact), 1 thread = 1 image
// ---------------------------------------------------------------------------
__global__ __launch_bounds__(256) void k_heads(
    const float* __restrict__ exact4g,
    const float* __restrict__ sw1, const float* __restrict__ sb1,
    const float* __restrict__ sw2, const float* __restrict__ sb2,
    const float* __restrict__ ew1, const float* __restrict__ eb1,
    const float* __restrict__ ew2, const float* __restrict__ eb2,
    const float* __restrict__ ew3, const float* __restrict__ eb3,
    const float* __restrict__ mem,
    float* __restrict__ out, int bsz)
{
    const int img = blockIdx.x * 256 + threadIdx.x;
    const float4 f = *(const float4*)(exact4g + (size_t)img * 4);
    const float f0 = f.x, f1 = f.y, f2 = f.z, f3 = f.w;
    const int off_samp = bsz * 4;
    const int off_reg  = bsz * 6;
    const int off_ker  = bsz * 7;

    float qq = f0 * f0 + f1 * f1 + f2 * f2 + f3 * f3;
    #pragma unroll
    for (int j = 0; j < 10; ++j) {
        float m0 = mem[j * 4 + 0], m1 = mem[j * 4 + 1];
        float m2 = mem[j * 4 + 2], m3 = mem[j * 4 + 3];
        float sq = qq + m0 * m0 + m1 * m1 + m2 * m2 + m3 * m3
                 - 2.f * (f0 * m0 + f1 * m1 + f2 * m2 + f3 * m3);
        out[off_ker + (size_t)img * 10 + j] = expf(-sq);
    }
    {
        float t1[4];
        #pragma unroll
        for (int j = 0; j < 4; ++j)
            t1[j] = tanhf(f0 * sw1[j * 2] + f1 * sw1[j * 2 + 1] + sb1[j]);
        float s0 = sb2[0], s1v = sb2[1];
        #pragma unroll
        for (int j = 0; j < 4; ++j) { s0 += t1[j] * sw2[j]; s1v += t1[j] * sw2[4 + j]; }
        float mx = fmaxf(s0, s1v);
        float e0 = expf(s0 - mx), e1 = expf(s1v - mx);
        float inv = 1.f / (e0 + e1);
        out[off_samp + (size_t)img * 2 + 0] = e0 * inv;
        out[off_samp + (size_t)img * 2 + 1] = e1 * inv;
    }
    {
        float e1a[8];
        #pragma unroll
        for (int j = 0; j < 8; ++j)
            e1a[j] = tanhf(f0 * ew1[j * 2] + f1 * ew1[j * 2 + 1] + eb1[j]);
        float rg = eb3[0];
        #pragma unroll
        for (int m = 0; m < 4; ++m) {
            float a = eb2[m];
            #pragma unroll
            for (int j = 0; j < 8; ++j) a += e1a[j] * ew2[m * 8 + j];
            rg += tanhf(a) * ew3[m];
        }
        out[off_reg + img] = rg;
    }
}

// ---------------------------------------------------------------------------
// Kernel 4: fc1 (MFMA bf16, M=bsz N=64 K=800) + relu + fc2 fused -> fct[4][bsz]
// ---------------------------------------------------------------------------
__global__ __launch_bounds__(128) void k_fc(
    const unsigned short* __restrict__ flatb, const unsigned short* __restrict__ Bp,
    const float* __restrict__ fc1b, const float* __restrict__ fc2w,
    const float* __restrict__ fc2b, float* __restrict__ fct, int bsz)
{
    __shared__ float h[2][16][68];

    const int tid  = threadIdx.x;
    const int w    = __builtin_amdgcn_readfirstlane(tid >> 6);
    const int l    = tid & 63;
    const int img0 = blockIdx.x * 32 + w * 16;
    const int m15  = l & 15;
    const int grp  = l >> 4;

    const unsigned short* aptr = flatb + (size_t)(img0 + m15) * 800 + grp * 8;
    const unsigned short* bptr = Bp + (size_t)l * 8;

    f32x4 acc[4] = {};
    for (int kb = 0; kb < 25; ++kb) {
        bf16x8 a = *(const bf16x8*)(aptr + kb * 32);
        #pragma unroll
        for (int nf = 0; nf < 4; ++nf) {
            bf16x8 b = *(const bf16x8*)(bptr + (size_t)(kb * 4 + nf) * 64 * 8);
            acc[nf] = __builtin_amdgcn_mfma_f32_16x16x32_bf16(a, b, acc[nf], 0, 0, 0);
        }
    }

    #pragma unroll
    for (int nf = 0; nf < 4; ++nf) {
        int j = nf * 16 + m15;
        float bj = fc1b[j];
        #pragma unroll
        for (int r = 0; r < 4; ++r)
            h[w][grp * 4 + r][j] = fmaxf(acc[nf][r] + bj, 0.f);
    }
    __syncthreads();

    {
        int im = m15, ch = grp;
        float a = fc2b[ch];
        const float* hp = &h[w][im][0];
        const float* wp = &fc2w[ch * 64];
        #pragma unroll 8
        for (int o = 0; o < 64; ++o) a += hp[o] * wp[o];
        fct[(size_t)ch * bsz + img0 + im] = a;
    }
}

// ---------------------------------------------------------------------------
// Kernel 5: BN partials — 64 blocks = (channel, segment)
// ---------------------------------------------------------------------------
__global__ __launch_bounds__(256) void k_bnred1(
    const float* __restrict__ fct, float* __restrict__ partial, int bsz)
{
    const int tid = threadIdx.x;
    const int ch  = blockIdx.x & 3;
    const int seg = blockIdx.x >> 2;
    const int n   = bsz / 16;
    const float* p = fct + (size_t)ch * bsz + seg * n;
    float s = 0.f, ss = 0.f;
    for (int i = tid; i < n; i += 256) {
        float v = p[i];
        s += v; ss += v * v;
    }
    __shared__ float rs[256], rss[256];
    rs[tid] = s; rss[tid] = ss;
    __syncthreads();
    for (int off = 128; off >= 1; off >>= 1) {
        if (tid < off) { rs[tid] += rs[tid + off]; rss[tid] += rss[tid + off]; }
        __syncthreads();
    }
    if (tid == 0) {
        partial[blockIdx.x * 2]     = rs[0];
        partial[blockIdx.x * 2 + 1] = rss[0];
    }
}

// ---------------------------------------------------------------------------
// Kernel 6: BN finalize + apply (bnred2 folded in, redundant per block)
// ---------------------------------------------------------------------------
__global__ __launch_bounds__(256) void k_bnfinal(
    const float* __restrict__ partial, const float* __restrict__ g,
    const float* __restrict__ bb, const float* __restrict__ fct,
    float* __restrict__ out, int bsz)
{
    __shared__ float sc[4], sh[4];
    const int tid = threadIdx.x;
    if (tid < 4) {
        float s = 0.f, ss = 0.f;
        for (int seg = 0; seg < 16; ++seg) {
            s  += partial[(seg * 4 + tid) * 2];
            ss += partial[(seg * 4 + tid) * 2 + 1];
        }
        float n = (float)bsz;
        float mu  = s / n;
        float var = ss / n - mu * mu;
        float scale = g[tid] * rsqrtf(var + EPS_BN);
        sc[tid] = scale;
        sh[tid] = bb[tid] - mu * scale;
    }
    __syncthreads();
    const int img = blockIdx.x * 256 + tid;
    float4 r;
    r.x = fct[img]           * sc[0] + sh[0];
    r.y = fct[bsz + img]     * sc[1] + sh[1];
    r.z = fct[2 * bsz + img] * sc[2] + sh[2];
    r.w = fct[3 * bsz + img] * sc[3] + sh[3];
    *(float4*)(out + (size_t)img * 4) = r;
}

// ---------------------------------------------------------------------------
extern "C" void kernel_launch(void* const* d_in, const int* in_sizes, int n_in,
                              void* d_out, int out_size, void* d_ws, size_t ws_size,
                              hipStream_t stream) {
    const float* x     = (const float*)d_in[0];
    const float* c1w   = (const float*)d_in[1];
    const float* c1b   = (const float*)d_in[2];
    const float* c2w   = (const float*)d_in[3];
    const float* c2b   = (const float*)d_in[4];
    const float* fc1w  = (const float*)d_in[5];
    const float* fc1b  = (const float*)d_in[6];
    const float* fc2w  = (const float*)d_in[7];
    const float* fc2b  = (const float*)d_in[8];
    const float* bng   = (const float*)d_in[9];
    const float* bnb   = (const float*)d_in[10];
    const float* sw1   = (const float*)d_in[11];
    const float* sb1   = (const float*)d_in[12];
    const float* sw2   = (const float*)d_in[13];
    const float* sb2   = (const float*)d_in[14];
    const float* ew1   = (const float*)d_in[15];
    const float* eb1   = (const float*)d_in[16];
    const float* ew2   = (const float*)d_in[17];
    const float* eb2   = (const float*)d_in[18];
    const float* ew3   = (const float*)d_in[19];
    const float* eb3   = (const float*)d_in[20];
    const float* mem   = (const float*)d_in[21];

    const int bsz = in_sizes[0] / 784;         // 8192
    float* out = (float*)d_out;

    unsigned short* flatb = (unsigned short*)d_ws;           // bsz*800 bf16
    unsigned short* Bp    = flatb + (size_t)bsz * 800;       // 51200 bf16
    unsigned short* Bc2   = Bp + 51200;                      // 1536 bf16
    float* fct            = (float*)(Bc2 + 1536);            // 4*bsz
    float* partial        = fct + (size_t)bsz * 4;           // 128
    float* exact4g        = partial + 128;                   // 4*bsz

    k_prep<<<201, 256, 0, stream>>>(fc1w, c2w, Bp, Bc2);
    k_conv<<<bsz / 2, 256, 0, stream>>>(x, c1w, c1b, c2w, c2b, Bc2,
                                        flatb, exact4g, bsz);
    k_heads<<<bsz / 256, 256, 0, stream>>>(exact4g, sw1, sb1, sw2, sb2,
                                           ew1, eb1, ew2, eb2, ew3, eb3, mem,
                                           out, bsz);
    k_fc<<<bsz / 32, 128, 0, stream>>>(flatb, Bp, fc1b, fc2w, fc2b, fct, bsz);
    k_bnred1<<<64, 256, 0, stream>>>(fct, partial, bsz);
    k_bnfinal<<<bsz / 256, 256, 0, stream>>>(partial, bng, bnb, fct, out, bsz);
}

// Round 10
// 50.103 us; speedup vs baseline: 3.3198x; 1.1284x over previous
//
#include <hip/hip_runtime.h>
#include <math.h>

#define EPS_BN 1e-5f

typedef float  f32x4  __attribute__((ext_vector_type(4)));
typedef float  f32x2  __attribute__((ext_vector_type(2)));
typedef short  bf16x8 __attribute__((ext_vector_type(8)));

__device__ inline unsigned short f2bf(float f) {
    union { float f; unsigned u; } c; c.f = f;
    unsigned u = c.u;
    return (unsigned short)((u + 0x7FFFu + ((u >> 16) & 1u)) >> 16);  // RNE
}

// ---------------------------------------------------------------------------
// Kernel 1: conv1(pk_fma) + conv2(MFMA) + bf16 flat + exact4 — 2 img/block.
//   Also: blocks 0..199 pack fc1_w -> Bp (MFMA B-frag); conv2 frags packed
//   per-block into LDS from c2w (k_prep eliminated).
// ---------------------------------------------------------------------------
__global__ __launch_bounds__(256, 8) void k_conv(
    const float* __restrict__ x,
    const float* __restrict__ c1w, const float* __restrict__ c1b,
    const float* __restrict__ c2w, const float* __restrict__ c2b,
    const float* __restrict__ fc1w, unsigned short* __restrict__ Bp,
    unsigned short* __restrict__ flatb, float* __restrict__ exact4g, int bsz)
{
    __shared__ float sx[2][900];                          // 30x30 halo input; later flat(bf16)
    __shared__ __align__(16) unsigned short s1t[2][16][16][8]; // bf16 conv1 out, halo
    __shared__ float s1f[2][4][12][8];                    // f32 corner for exact heads
    __shared__ __align__(16) unsigned short sBc2[1536];   // conv2 B-fragments

    const int tid  = threadIdx.x;
    const int img0 = blockIdx.x * 2;

    // ---- fold of k_prep: blocks 0..199 pack Bp (fc1 weights)
    if (blockIdx.x < 200) {
        int t = blockIdx.x * 256 + tid;        // < 51200
        int j  = t & 7;
        int l  = (t >> 3) & 63;
        int nf = (t >> 9) & 3;
        int kb = t >> 11;
        int k  = kb * 32 + (l >> 4) * 8 + j;
        int o  = nf * 16 + (l & 15);
        float v = (k < 784) ? fc1w[o * 784 + k] : 0.f;
        Bp[t] = f2bf(v);
    }

    // ---- pack conv2 weights into LDS fragments
    for (int t = tid; t < 1536; t += 256) {
        int j  = t & 7;            // ic
        int l  = (t >> 3) & 63;
        int g  = t >> 9;           // k-group
        int kp = 4 * g + (l >> 4); // kernel position
        int oc = l & 15;
        float v = (kp < 9) ? c2w[(oc * 8 + j) * 9 + kp] : 0.f;
        sBc2[t] = f2bf(v);
    }

    // ---- zero input halo
    if (tid < 232) {
        int im = tid / 116;
        int r  = tid - im * 116;
        int idx;
        if      (r < 30) idx = r;
        else if (r < 60) idx = 29 * 30 + (r - 30);
        else if (r < 88) idx = (r - 60 + 1) * 30;
        else             idx = (r - 88 + 1) * 30 + 29;
        sx[im][idx] = 0.f;
    }
    // ---- stage interior
    const float* xb = x + (size_t)img0 * 784;
    for (int i = tid; i < 1568; i += 256) {
        int im = i / 784;
        int j  = i - im * 784;
        sx[im][(j / 28 + 1) * 30 + (j % 28) + 1] = xb[i];
    }
    // ---- zero s1t halo
    for (int q = tid; q < 120; q += 256) {
        int im = q / 60, r = q - im * 60;
        int Y, X;
        if      (r < 16) { Y = 0;          X = r; }
        else if (r < 32) { Y = 15;         X = r - 16; }
        else if (r < 46) { Y = r - 32 + 1; X = 0; }
        else             { Y = r - 46 + 1; X = 15; }
        *(uint4*)&s1t[im][Y][X][0] = make_uint4(0, 0, 0, 0);
    }
    // ---- zero s1f
    for (int q = tid; q < 192; q += 256) ((float4*)s1f)[q] = make_float4(0, 0, 0, 0);
    __syncthreads();

    // ---- conv1 (1->8) + relu + pool via v_pk_fma_f32: 196 tasks = (img,py,pxq)
    if (tid < 196) {
        int im  = tid / 98;
        int r   = tid - im * 98;
        int py  = r / 7;
        int pxq = r - py * 7;
        const float* sp = &sx[im][(2 * py) * 30 + 4 * pxq];  // 8B-aligned base
        f32x2 rp[4][3], sh[4][2];
        #pragma unroll
        for (int wy = 0; wy < 4; ++wy) {
            rp[wy][0] = *(const f32x2*)(sp + wy * 30);
            rp[wy][1] = *(const f32x2*)(sp + wy * 30 + 2);
            rp[wy][2] = *(const f32x2*)(sp + wy * 30 + 4);
            sh[wy][0] = (f32x2){rp[wy][0].y, rp[wy][1].x};   // (w1,w2)
            sh[wy][1] = (f32x2){rp[wy][1].y, rp[wy][2].x};   // (w3,w4)
        }
        unsigned pk0[4] = {0, 0, 0, 0}, pk1[4] = {0, 0, 0, 0};
        const bool sf = (py <= 2) && (pxq <= 4);
        #pragma unroll
        for (int c = 0; c < 8; ++c) {
            const float* wp = &c1w[c * 9];            // uniform -> s_load
            float bb = c1b[c];
            f32x2 A[2][2];                             // [q][dy], lanes = dx
            A[0][0] = (f32x2){bb, bb}; A[0][1] = (f32x2){bb, bb};
            A[1][0] = (f32x2){bb, bb}; A[1][1] = (f32x2){bb, bb};
            #pragma unroll
            for (int ky = 0; ky < 3; ++ky) {
                #pragma unroll
                for (int kx = 0; kx < 3; ++kx) {
                    float wv = wp[ky * 3 + kx];
                    f32x2 wv2 = (f32x2){wv, wv};
                    #pragma unroll
                    for (int dy = 0; dy < 2; ++dy) {
                        int row = dy + ky;
                        f32x2 s0 = (kx == 0) ? rp[row][0] : (kx == 1) ? sh[row][0] : rp[row][1];
                        f32x2 s1v = (kx == 0) ? rp[row][1] : (kx == 1) ? sh[row][1] : rp[row][2];
                        A[0][dy] = __builtin_elementwise_fma(s0,  wv2, A[0][dy]);
                        A[1][dy] = __builtin_elementwise_fma(s1v, wv2, A[1][dy]);
                    }
                }
            }
            f32x2 m0 = __builtin_elementwise_max(A[0][0], A[0][1]);
            f32x2 m1 = __builtin_elementwise_max(A[1][0], A[1][1]);
            float v0 = fmaxf(fmaxf(m0.x, m0.y), 0.f);
            float v1 = fmaxf(fmaxf(m1.x, m1.y), 0.f);
            pk0[c >> 1] |= (unsigned)f2bf(v0) << ((c & 1) * 16);
            pk1[c >> 1] |= (unsigned)f2bf(v1) << ((c & 1) * 16);
            if (sf) {
                s1f[im][py + 1][2 * pxq + 1][c] = v0;
                s1f[im][py + 1][2 * pxq + 2][c] = v1;
            }
        }
        *(uint4*)&s1t[im][py + 1][2 * pxq + 1][0] = make_uint4(pk0[0], pk0[1], pk0[2], pk0[3]);
        *(uint4*)&s1t[im][py + 1][2 * pxq + 2][0] = make_uint4(pk1[0], pk1[1], pk1[2], pk1[3]);
    }
    __syncthreads();

    // ---- conv2 (8->16) + relu + pool via MFMA, quad-major M ordering
    {
        const int wv   = __builtin_amdgcn_readfirstlane(tid >> 6);
        const int im   = wv >> 1;
        const int half = wv & 1;
        const int l    = tid & 63;
        const int grp  = l >> 4;
        const int m15  = l & 15;

        bf16x8 bfr[3];
        #pragma unroll
        for (int g = 0; g < 3; ++g)
            bfr[g] = *(const bf16x8*)(sBc2 + (size_t)(g * 64 + l) * 8);

        int koff[3];
        #pragma unroll
        for (int g = 0; g < 3; ++g) {
            int kp = 4 * g + grp;
            koff[g] = (kp < 9) ? ((kp / 3) * 16 + (kp % 3)) * 8 : 0;
        }
        const float bias = c2b[m15];
        unsigned short* s2b = (unsigned short*)&sx[im][0];   // input dead -> bf16 flat

        for (int t = half; t < 13; t += 2) {
            int qa = 4 * t + (m15 >> 2);
            if (qa > 48) qa = 48;                // pad rows replicate row q=48
            int s  = m15 & 3;
            int py = qa / 7, px = qa - 7 * py;
            int y  = 2 * py + (s >> 1), xx = 2 * px + (s & 1);
            const unsigned short* ab = &s1t[im][y][xx][0];
            f32x4 acc = {};
            #pragma unroll
            for (int g = 0; g < 3; ++g) {
                bf16x8 a = *(const bf16x8*)(ab + koff[g]);
                acc = __builtin_amdgcn_mfma_f32_16x16x32_bf16(a, bfr[g], acc, 0, 0, 0);
            }
            float m = fmaxf(fmaxf(acc[0], acc[1]), fmaxf(acc[2], acc[3]));
            float val = fmaxf(m + bias, 0.f);
            int qo = 4 * t + grp;                // lane's output quad
            if (qo < 49) s2b[m15 * 49 + qo] = f2bf(val);
        }

        // ---- exact fp32 flat[:4] (ch 0, quads 0..3) on waves 1,3 lanes 0..15
        if (half == 1 && l < 16) {
            int q  = l >> 2;
            int dy = (l >> 1) & 1, dx = l & 1;
            float a = 0.f;
            #pragma unroll
            for (int kp = 0; kp < 9; ++kp) {
                int ky = kp / 3, kx = kp - 3 * ky;
                const float* spf = &s1f[im][dy + ky][2 * q + dx + kx][0];
                #pragma unroll
                for (int ic = 0; ic < 8; ++ic)
                    a += spf[ic] * c2w[ic * 9 + kp];   // uniform -> s_load
            }
            float m1 = fmaxf(a, __shfl_xor(a, 1));
            float m2 = fmaxf(m1, __shfl_xor(m1, 2));
            if ((l & 3) == 0)
                exact4g[(size_t)(img0 + im) * 4 + q] = fmaxf(m2 + c2b[0], 0.f);
        }
    }
    __syncthreads();

    // ---- flat copy LDS(bf16) -> global, rows padded to 800 (u32 = 2 vals)
    for (int i = tid; i < 2 * 400; i += 256) {
        int im = i / 400;
        int j  = i - im * 400;                    // u32 index within row
        const unsigned short* s2b = (const unsigned short*)&sx[im][0];
        unsigned pk = (j < 392) ? *(const unsigned*)(s2b + 2 * j) : 0u;
        *(unsigned*)(flatb + (size_t)(img0 + im) * 800 + 2 * j) = pk;
    }
}

// ---------------------------------------------------------------------------
// Kernel 2: fc1 (MFMA bf16) + relu + fc2 fused -> fct[4][bsz] + BN partials
// ---------------------------------------------------------------------------
__global__ __launch_bounds__(128) void k_fc(
    const unsigned short* __restrict__ flatb, const unsigned short* __restrict__ Bp,
    const float* __restrict__ fc1b, const float* __restrict__ fc2w,
    const float* __restrict__ fc2b, float* __restrict__ fct,
    float* __restrict__ partial, int bsz)
{
    __shared__ float h[2][16][68];
    __shared__ float ps[2][4][2];

    const int tid  = threadIdx.x;
    const int w    = __builtin_amdgcn_readfirstlane(tid >> 6);
    const int l    = tid & 63;
    const int img0 = blockIdx.x * 32 + w * 16;
    const int m15  = l & 15;
    const int grp  = l >> 4;

    const unsigned short* aptr = flatb + (size_t)(img0 + m15) * 800 + grp * 8;
    const unsigned short* bptr = Bp + (size_t)l * 8;

    f32x4 acc[4] = {};
    for (int kb = 0; kb < 25; ++kb) {
        bf16x8 a = *(const bf16x8*)(aptr + kb * 32);
        #pragma unroll
        for (int nf = 0; nf < 4; ++nf) {
            bf16x8 b = *(const bf16x8*)(bptr + (size_t)(kb * 4 + nf) * 64 * 8);
            acc[nf] = __builtin_amdgcn_mfma_f32_16x16x32_bf16(a, b, acc[nf], 0, 0, 0);
        }
    }

    #pragma unroll
    for (int nf = 0; nf < 4; ++nf) {
        int j = nf * 16 + m15;
        float bj = fc1b[j];
        #pragma unroll
        for (int r = 0; r < 4; ++r)
            h[w][grp * 4 + r][j] = fmaxf(acc[nf][r] + bj, 0.f);
    }
    __syncthreads();

    {
        int im = m15, ch = grp;
        float a = fc2b[ch];
        const float* hp = &h[w][im][0];
        const float* wp = &fc2w[ch * 64];
        #pragma unroll 8
        for (int o = 0; o < 64; ++o) a += hp[o] * wp[o];
        fct[(size_t)ch * bsz + img0 + im] = a;

        // BN partial: reduce over the 16 images in this wave (lanes l&15)
        float s = a, ss = a * a;
        #pragma unroll
        for (int off = 1; off < 16; off <<= 1) {
            s  += __shfl_xor(s,  off);
            ss += __shfl_xor(ss, off);
        }
        if (m15 == 0) { ps[w][ch][0] = s; ps[w][ch][1] = ss; }
    }
    __syncthreads();

    if (tid < 8) {
        int c = tid & 3, st = tid >> 2;
        partial[(size_t)blockIdx.x * 8 + st * 4 + c] =
            ps[0][c][st] + ps[1][c][st];
    }
}

// ---------------------------------------------------------------------------
// Kernel 3: BN finalize (reduce 256 partials) + heads + BN apply — 32 blocks
// ---------------------------------------------------------------------------
__global__ __launch_bounds__(256) void k_bnheads(
    const float* __restrict__ partial, const float* __restrict__ g,
    const float* __restrict__ bb, const float* __restrict__ fct,
    const float* __restrict__ exact4g,
    const float* __restrict__ sw1, const float* __restrict__ sb1,
    const float* __restrict__ sw2, const float* __restrict__ sb2,
    const float* __restrict__ ew1, const float* __restrict__ eb1,
    const float* __restrict__ ew2, const float* __restrict__ eb2,
    const float* __restrict__ ew3, const float* __restrict__ eb3,
    const float* __restrict__ mem,
    float* __restrict__ out, int bsz)
{
    __shared__ float red[32][8];
    __shared__ float tot[8];
    __shared__ float sc[4], shf[4];

    const int tid = threadIdx.x;

    // ---- stage 1: 32 chunks x 8 values
    {
        int v = tid & 7, chunk = tid >> 3;
        float s = 0.f;
        #pragma unroll
        for (int i = 0; i < 8; ++i)
            s += partial[(size_t)(chunk * 8 + i) * 8 + v];
        red[chunk][v] = s;
    }
    __syncthreads();
    if (tid < 8) {
        float s = 0.f;
        #pragma unroll 8
        for (int c = 0; c < 32; ++c) s += red[c][tid];
        tot[tid] = s;
    }
    __syncthreads();
    if (tid < 4) {
        float n = (float)bsz;
        float mu  = tot[tid] / n;
        float var = tot[4 + tid] / n - mu * mu;
        float scale = g[tid] * rsqrtf(var + EPS_BN);
        sc[tid]  = scale;
        shf[tid] = bb[tid] - mu * scale;
    }
    __syncthreads();

    const int img = blockIdx.x * 256 + tid;
    const int off_samp = bsz * 4;
    const int off_reg  = bsz * 6;
    const int off_ker  = bsz * 7;

    // ---- heads (fp32 exact)
    {
        const float4 f = *(const float4*)(exact4g + (size_t)img * 4);
        const float f0 = f.x, f1 = f.y, f2 = f.z, f3 = f.w;
        float qq = f0 * f0 + f1 * f1 + f2 * f2 + f3 * f3;
        #pragma unroll
        for (int j = 0; j < 10; ++j) {
            float m0 = mem[j * 4 + 0], m1 = mem[j * 4 + 1];
            float m2 = mem[j * 4 + 2], m3 = mem[j * 4 + 3];
            float sq = qq + m0 * m0 + m1 * m1 + m2 * m2 + m3 * m3
                     - 2.f * (f0 * m0 + f1 * m1 + f2 * m2 + f3 * m3);
            out[off_ker + (size_t)img * 10 + j] = expf(-sq);
        }
        {
            float t1[4];
            #pragma unroll
            for (int j = 0; j < 4; ++j)
                t1[j] = tanhf(f0 * sw1[j * 2] + f1 * sw1[j * 2 + 1] + sb1[j]);
            float s0 = sb2[0], s1v = sb2[1];
            #pragma unroll
            for (int j = 0; j < 4; ++j) { s0 += t1[j] * sw2[j]; s1v += t1[j] * sw2[4 + j]; }
            float mx = fmaxf(s0, s1v);
            float e0 = expf(s0 - mx), e1 = expf(s1v - mx);
            float inv = 1.f / (e0 + e1);
            out[off_samp + (size_t)img * 2 + 0] = e0 * inv;
            out[off_samp + (size_t)img * 2 + 1] = e1 * inv;
        }
        {
            float e1a[8];
            #pragma unroll
            for (int j = 0; j < 8; ++j)
                e1a[j] = tanhf(f0 * ew1[j * 2] + f1 * ew1[j * 2 + 1] + eb1[j]);
            float rg = eb3[0];
            #pragma unroll
            for (int m = 0; m < 4; ++m) {
                float a = eb2[m];
                #pragma unroll
                for (int j = 0; j < 8; ++j) a += e1a[j] * ew2[m * 8 + j];
                rg += tanhf(a) * ew3[m];
            }
            out[off_reg + img] = rg;
        }
    }

    // ---- BN apply -> logits
    {
        float4 r;
        r.x = fct[img]           * sc[0] + shf[0];
        r.y = fct[bsz + img]     * sc[1] + shf[1];
        r.z = fct[2 * bsz + img] * sc[2] + shf[2];
        r.w = fct[3 * bsz + img] * sc[3] + shf[3];
        *(float4*)(out + (size_t)img * 4) = r;
    }
}

// ---------------------------------------------------------------------------
extern "C" void kernel_launch(void* const* d_in, const int* in_sizes, int n_in,
                              void* d_out, int out_size, void* d_ws, size_t ws_size,
                              hipStream_t stream) {
    const float* x     = (const float*)d_in[0];
    const float* c1w   = (const float*)d_in[1];
    const float* c1b   = (const float*)d_in[2];
    const float* c2w   = (const float*)d_in[3];
    const float* c2b   = (const float*)d_in[4];
    const float* fc1w  = (const float*)d_in[5];
    const float* fc1b  = (const float*)d_in[6];
    const float* fc2w  = (const float*)d_in[7];
    const float* fc2b  = (const float*)d_in[8];
    const float* bng   = (const float*)d_in[9];
    const float* bnb   = (const float*)d_in[10];
    const float* sw1   = (const float*)d_in[11];
    const float* sb1   = (const float*)d_in[12];
    const float* sw2   = (const float*)d_in[13];
    const float* sb2   = (const float*)d_in[14];
    const float* ew1   = (const float*)d_in[15];
    const float* eb1   = (const float*)d_in[16];
    const float* ew2   = (const float*)d_in[17];
    const float* eb2   = (const float*)d_in[18];
    const float* ew3   = (const float*)d_in[19];
    const float* eb3   = (const float*)d_in[20];
    const float* mem   = (const float*)d_in[21];

    const int bsz = in_sizes[0] / 784;         // 8192
    float* out = (float*)d_out;

    unsigned short* flatb = (unsigned short*)d_ws;           // bsz*800 bf16
    unsigned short* Bp    = flatb + (size_t)bsz * 800;       // 51200 bf16
    float* fct            = (float*)(Bp + 51200);            // 4*bsz
    float* partial        = fct + (size_t)bsz * 4;           // 256*8
    float* exact4g        = partial + 2048;                  // 4*bsz

    k_conv<<<bsz / 2, 256, 0, stream>>>(x, c1w, c1b, c2w, c2b,
                                        fc1w, Bp, flatb, exact4g, bsz);
    k_fc<<<bsz / 32, 128, 0, stream>>>(flatb, Bp, fc1b, fc2w, fc2b,
                                       fct, partial, bsz);
    k_bnheads<<<bsz / 256, 256, 0, stream>>>(partial, bng, bnb, fct, exact4g,
                                             sw1, sb1, sw2, sb2,
                                             ew1, eb1, ew2, eb2, ew3, eb3, mem,
                                             out, bsz);
}

// Round 11
// 45.694 us; speedup vs baseline: 3.6401x; 1.0965x over previous
//
#include <hip/hip_runtime.h>
#include <math.h>

#define EPS_BN 1e-5f

typedef float  f32x4  __attribute__((ext_vector_type(4)));
typedef float  f32x2  __attribute__((ext_vector_type(2)));
typedef short  bf16x8 __attribute__((ext_vector_type(8)));

__device__ inline unsigned short f2bf(float f) {
    union { float f; unsigned u; } c; c.f = f;
    unsigned u = c.u;
    return (unsigned short)((u + 0x7FFFu + ((u >> 16) & 1u)) >> 16);  // RNE
}

// ---------------------------------------------------------------------------
// Kernel 1: conv1(pk_fma) + conv2(MFMA, LUT-addressed) + bf16 flat + exact4
//   2 img/block; blocks 0..199 also pack fc1_w -> Bp (MFMA B-frag).
// ---------------------------------------------------------------------------
__global__ __launch_bounds__(256, 8) void k_conv(
    const float* __restrict__ x,
    const float* __restrict__ c1w, const float* __restrict__ c1b,
    const float* __restrict__ c2w, const float* __restrict__ c2b,
    const float* __restrict__ fc1w, unsigned short* __restrict__ Bp,
    unsigned short* __restrict__ flatb, float* __restrict__ exact4g, int bsz)
{
    __shared__ float sx[2][900];                          // 30x30 halo input; later flat(bf16)
    __shared__ __align__(16) unsigned short s1t[2][16][16][8]; // bf16 conv1 out, halo
    __shared__ float s1f[2][4][12][8];                    // f32 corner for exact heads
    __shared__ __align__(16) unsigned short sBc2[1536];   // conv2 B-fragments
    __shared__ unsigned short lut16[56];                  // qa -> elem offset in s1t

    const int tid  = threadIdx.x;
    const int img0 = blockIdx.x * 2;

    // ---- blocks 0..199 pack Bp (fc1 weights)
    if (blockIdx.x < 200) {
        int t = blockIdx.x * 256 + tid;        // < 51200
        int j  = t & 7;
        int l  = (t >> 3) & 63;
        int nf = (t >> 9) & 3;
        int kb = t >> 11;
        int k  = kb * 32 + (l >> 4) * 8 + j;
        int o  = nf * 16 + (l & 15);
        float v = (k < 784) ? fc1w[o * 784 + k] : 0.f;
        Bp[t] = f2bf(v);
    }

    // ---- pack conv2 weights into LDS fragments
    for (int t = tid; t < 1536; t += 256) {
        int j  = t & 7;            // ic
        int l  = (t >> 3) & 63;
        int g  = t >> 9;           // k-group
        int kp = 4 * g + (l >> 4); // kernel position
        int oc = l & 15;
        float v = (kp < 9) ? c2w[(oc * 8 + j) * 9 + kp] : 0.f;
        sBc2[t] = f2bf(v);
    }

    // ---- conv2 address LUT: quad qa -> element offset (row-pair, col-pair)
    if (tid < 52) lut16[tid] = (unsigned short)(256 * (tid / 7) + 16 * (tid % 7));

    // ---- zero input halo
    if (tid < 232) {
        int im = tid / 116;
        int r  = tid - im * 116;
        int idx;
        if      (r < 30) idx = r;
        else if (r < 60) idx = 29 * 30 + (r - 30);
        else if (r < 88) idx = (r - 60 + 1) * 30;
        else             idx = (r - 88 + 1) * 30 + 29;
        sx[im][idx] = 0.f;
    }
    // ---- stage interior via float4 (392 tasks)
    {
        const float4* xb4 = (const float4*)(x + (size_t)img0 * 784);
        for (int i = tid; i < 392; i += 256) {
            int im  = i / 196;
            int j   = i - im * 196;          // float4 index in image
            int row = j / 7;
            int c4  = j - row * 7;
            float4 f = xb4[i];
            float* dp = &sx[im][(row + 1) * 30 + c4 * 4 + 1];
            dp[0] = f.x; dp[1] = f.y; dp[2] = f.z; dp[3] = f.w;
        }
    }
    // ---- zero s1t halo
    for (int q = tid; q < 120; q += 256) {
        int im = q / 60, r = q - im * 60;
        int Y, X;
        if      (r < 16) { Y = 0;          X = r; }
        else if (r < 32) { Y = 15;         X = r - 16; }
        else if (r < 46) { Y = r - 32 + 1; X = 0; }
        else             { Y = r - 46 + 1; X = 15; }
        *(uint4*)&s1t[im][Y][X][0] = make_uint4(0, 0, 0, 0);
    }
    // ---- zero s1f
    for (int q = tid; q < 192; q += 256) ((float4*)s1f)[q] = make_float4(0, 0, 0, 0);
    __syncthreads();

    // ---- conv1 (1->8) + relu + pool via v_pk_fma_f32: 196 tasks = (img,py,pxq)
    if (tid < 196) {
        int im  = tid / 98;
        int r   = tid - im * 98;
        int py  = r / 7;
        int pxq = r - py * 7;
        const float* sp = &sx[im][(2 * py) * 30 + 4 * pxq];  // 8B-aligned base
        f32x2 rp[4][3], sh[4][2];
        #pragma unroll
        for (int wy = 0; wy < 4; ++wy) {
            rp[wy][0] = *(const f32x2*)(sp + wy * 30);
            rp[wy][1] = *(const f32x2*)(sp + wy * 30 + 2);
            rp[wy][2] = *(const f32x2*)(sp + wy * 30 + 4);
            sh[wy][0] = (f32x2){rp[wy][0].y, rp[wy][1].x};   // (w1,w2)
            sh[wy][1] = (f32x2){rp[wy][1].y, rp[wy][2].x};   // (w3,w4)
        }
        unsigned pk0[4] = {0, 0, 0, 0}, pk1[4] = {0, 0, 0, 0};
        const bool sf = (py <= 2) && (pxq <= 4);
        #pragma unroll
        for (int c = 0; c < 8; ++c) {
            const float* wp = &c1w[c * 9];            // uniform -> s_load
            float bb = c1b[c];
            f32x2 A[2][2];                             // [q][dy], lanes = dx
            A[0][0] = (f32x2){bb, bb}; A[0][1] = (f32x2){bb, bb};
            A[1][0] = (f32x2){bb, bb}; A[1][1] = (f32x2){bb, bb};
            #pragma unroll
            for (int ky = 0; ky < 3; ++ky) {
                #pragma unroll
                for (int kx = 0; kx < 3; ++kx) {
                    float wv = wp[ky * 3 + kx];
                    f32x2 wv2 = (f32x2){wv, wv};
                    #pragma unroll
                    for (int dy = 0; dy < 2; ++dy) {
                        int row = dy + ky;
                        f32x2 s0 = (kx == 0) ? rp[row][0] : (kx == 1) ? sh[row][0] : rp[row][1];
                        f32x2 s1v = (kx == 0) ? rp[row][1] : (kx == 1) ? sh[row][1] : rp[row][2];
                        A[0][dy] = __builtin_elementwise_fma(s0,  wv2, A[0][dy]);
                        A[1][dy] = __builtin_elementwise_fma(s1v, wv2, A[1][dy]);
                    }
                }
            }
            f32x2 m0 = __builtin_elementwise_max(A[0][0], A[0][1]);
            f32x2 m1 = __builtin_elementwise_max(A[1][0], A[1][1]);
            float v0 = fmaxf(fmaxf(m0.x, m0.y), 0.f);
            float v1 = fmaxf(fmaxf(m1.x, m1.y), 0.f);
            pk0[c >> 1] |= (unsigned)f2bf(v0) << ((c & 1) * 16);
            pk1[c >> 1] |= (unsigned)f2bf(v1) << ((c & 1) * 16);
            if (sf) {
                s1f[im][py + 1][2 * pxq + 1][c] = v0;
                s1f[im][py + 1][2 * pxq + 2][c] = v1;
            }
        }
        *(uint4*)&s1t[im][py + 1][2 * pxq + 1][0] = make_uint4(pk0[0], pk0[1], pk0[2], pk0[3]);
        *(uint4*)&s1t[im][py + 1][2 * pxq + 2][0] = make_uint4(pk1[0], pk1[1], pk1[2], pk1[3]);
    }
    __syncthreads();

    // ---- conv2 (8->16) + relu + pool via MFMA, LUT-addressed quad-major M
    {
        const int wv   = __builtin_amdgcn_readfirstlane(tid >> 6);
        const int im   = wv >> 1;
        const int half = wv & 1;
        const int l    = tid & 63;
        const int grp  = l >> 4;
        const int m15  = l & 15;

        bf16x8 bfr[3];
        #pragma unroll
        for (int g = 0; g < 3; ++g)
            bfr[g] = *(const bf16x8*)(sBc2 + (size_t)(g * 64 + l) * 8);

        int koff[3];
        #pragma unroll
        for (int g = 0; g < 3; ++g) {
            int kp = 4 * g + grp;
            koff[g] = (kp < 9) ? ((kp / 3) * 16 + (kp % 3)) * 8 : 0;
        }
        const float bias = c2b[m15];
        unsigned short* s2b = (unsigned short*)&sx[im][0];   // input dead -> bf16 flat

        const int n   = 7 - half;                 // 7 iters for half=0, 6 for half=1
        const int qa0 = 4 * half + (m15 >> 2);
        const int sub = ((m15 & 2) >> 1) * 128 + (m15 & 1) * 8;  // s=(m15&3) offset
        const unsigned short* s1b = &s1t[im][0][0][0];

        unsigned roff[7];
        #pragma unroll
        for (int i = 0; i < 7; ++i) {
            if (i < n) {
                int qa = qa0 + 8 * i;
                if (qa > 48) qa = 48;             // replicate row 48 for pad lanes
                roff[i] = lut16[qa];
            }
        }

        int qo = 4 * half + grp;                  // output quad, +8 per iter
        #pragma unroll
        for (int i = 0; i < 7; ++i) {
            if (i < n) {
                const unsigned short* ab = s1b + roff[i] + sub;
                f32x4 acc = {};
                #pragma unroll
                for (int g = 0; g < 3; ++g) {
                    bf16x8 a = *(const bf16x8*)(ab + koff[g]);
                    acc = __builtin_amdgcn_mfma_f32_16x16x32_bf16(a, bfr[g], acc, 0, 0, 0);
                }
                float m = fmaxf(fmaxf(acc[0], acc[1]), fmaxf(acc[2], acc[3]));
                float val = fmaxf(m + bias, 0.f);
                if (qo < 49) s2b[m15 * 49 + qo] = f2bf(val);
                qo += 8;
            }
        }

        // ---- exact fp32 flat[:4] (ch 0, quads 0..3) on waves 1,3 lanes 0..15
        if (half == 1 && l < 16) {
            int q  = l >> 2;
            int dy = (l >> 1) & 1, dx = l & 1;
            float a = 0.f;
            #pragma unroll
            for (int kp = 0; kp < 9; ++kp) {
                int ky = kp / 3, kx = kp - 3 * ky;
                const float* spf = &s1f[im][dy + ky][2 * q + dx + kx][0];
                #pragma unroll
                for (int ic = 0; ic < 8; ++ic)
                    a += spf[ic] * c2w[ic * 9 + kp];   // uniform -> s_load
            }
            float m1 = fmaxf(a, __shfl_xor(a, 1));
            float m2 = fmaxf(m1, __shfl_xor(m1, 2));
            if ((l & 3) == 0)
                exact4g[(size_t)(img0 + im) * 4 + q] = fmaxf(m2 + c2b[0], 0.f);
        }
    }
    __syncthreads();

    // ---- flat copy LDS(bf16) -> global via uint4: 100 x 16B per image
    if (tid < 200) {
        int im = tid / 100;
        int j  = tid - im * 100;                  // uint4 index within row
        const uint4* s2v = (const uint4*)&sx[im][0];
        uint4 v = (j < 98) ? s2v[j] : make_uint4(0, 0, 0, 0);
        *(uint4*)(flatb + (size_t)(img0 + im) * 800 + j * 8) = v;
    }
}

// ---------------------------------------------------------------------------
// Kernel 2: fc1 (MFMA bf16) + relu + fc2 fused -> fct[4][bsz] + BN partials
// ---------------------------------------------------------------------------
__global__ __launch_bounds__(128) void k_fc(
    const unsigned short* __restrict__ flatb, const unsigned short* __restrict__ Bp,
    const float* __restrict__ fc1b, const float* __restrict__ fc2w,
    const float* __restrict__ fc2b, float* __restrict__ fct,
    float* __restrict__ partial, int bsz)
{
    __shared__ float h[2][16][68];
    __shared__ float ps[2][4][2];

    const int tid  = threadIdx.x;
    const int w    = __builtin_amdgcn_readfirstlane(tid >> 6);
    const int l    = tid & 63;
    const int img0 = blockIdx.x * 32 + w * 16;
    const int m15  = l & 15;
    const int grp  = l >> 4;

    const unsigned short* aptr = flatb + (size_t)(img0 + m15) * 800 + grp * 8;
    const unsigned short* bptr = Bp + (size_t)l * 8;

    f32x4 acc[4] = {};
    for (int kb = 0; kb < 25; ++kb) {
        bf16x8 a = *(const bf16x8*)(aptr + kb * 32);
        #pragma unroll
        for (int nf = 0; nf < 4; ++nf) {
            bf16x8 b = *(const bf16x8*)(bptr + (size_t)(kb * 4 + nf) * 64 * 8);
            acc[nf] = __builtin_amdgcn_mfma_f32_16x16x32_bf16(a, b, acc[nf], 0, 0, 0);
        }
    }

    #pragma unroll
    for (int nf = 0; nf < 4; ++nf) {
        int j = nf * 16 + m15;
        float bj = fc1b[j];
        #pragma unroll
        for (int r = 0; r < 4; ++r)
            h[w][grp * 4 + r][j] = fmaxf(acc[nf][r] + bj, 0.f);
    }
    __syncthreads();

    {
        int im = m15, ch = grp;
        float a = fc2b[ch];
        const float* hp = &h[w][im][0];
        const float* wp = &fc2w[ch * 64];
        #pragma unroll 8
        for (int o = 0; o < 64; ++o) a += hp[o] * wp[o];
        fct[(size_t)ch * bsz + img0 + im] = a;

        float s = a, ss = a * a;
        #pragma unroll
        for (int off = 1; off < 16; off <<= 1) {
            s  += __shfl_xor(s,  off);
            ss += __shfl_xor(ss, off);
        }
        if (m15 == 0) { ps[w][ch][0] = s; ps[w][ch][1] = ss; }
    }
    __syncthreads();

    if (tid < 8) {
        int c = tid & 3, st = tid >> 2;
        partial[(size_t)blockIdx.x * 8 + st * 4 + c] =
            ps[0][c][st] + ps[1][c][st];
    }
}

// ---------------------------------------------------------------------------
// Kernel 3: BN finalize + heads + BN apply — 32 blocks
// ---------------------------------------------------------------------------
__global__ __launch_bounds__(256) void k_bnheads(
    const float* __restrict__ partial, const float* __restrict__ g,
    const float* __restrict__ bb, const float* __restrict__ fct,
    const float* __restrict__ exact4g,
    const float* __restrict__ sw1, const float* __restrict__ sb1,
    const float* __restrict__ sw2, const float* __restrict__ sb2,
    const float* __restrict__ ew1, const float* __restrict__ eb1,
    const float* __restrict__ ew2, const float* __restrict__ eb2,
    const float* __restrict__ ew3, const float* __restrict__ eb3,
    const float* __restrict__ mem,
    float* __restrict__ out, int bsz)
{
    __shared__ float red[32][8];
    __shared__ float tot[8];
    __shared__ float sc[4], shf[4];

    const int tid = threadIdx.x;

    {
        int v = tid & 7, chunk = tid >> 3;
        float s = 0.f;
        #pragma unroll
        for (int i = 0; i < 8; ++i)
            s += partial[(size_t)(chunk * 8 + i) * 8 + v];
        red[chunk][v] = s;
    }
    __syncthreads();
    if (tid < 8) {
        float s = 0.f;
        #pragma unroll 8
        for (int c = 0; c < 32; ++c) s += red[c][tid];
        tot[tid] = s;
    }
    __syncthreads();
    if (tid < 4) {
        float n = (float)bsz;
        float mu  = tot[tid] / n;
        float var = tot[4 + tid] / n - mu * mu;
        float scale = g[tid] * rsqrtf(var + EPS_BN);
        sc[tid]  = scale;
        shf[tid] = bb[tid] - mu * scale;
    }
    __syncthreads();

    const int img = blockIdx.x * 256 + tid;
    const int off_samp = bsz * 4;
    const int off_reg  = bsz * 6;
    const int off_ker  = bsz * 7;

    {
        const float4 f = *(const float4*)(exact4g + (size_t)img * 4);
        const float f0 = f.x, f1 = f.y, f2 = f.z, f3 = f.w;
        float qq = f0 * f0 + f1 * f1 + f2 * f2 + f3 * f3;
        #pragma unroll
        for (int j = 0; j < 10; ++j) {
            float m0 = mem[j * 4 + 0], m1 = mem[j * 4 + 1];
            float m2 = mem[j * 4 + 2], m3 = mem[j * 4 + 3];
            float sq = qq + m0 * m0 + m1 * m1 + m2 * m2 + m3 * m3
                     - 2.f * (f0 * m0 + f1 * m1 + f2 * m2 + f3 * m3);
            out[off_ker + (size_t)img * 10 + j] = expf(-sq);
        }
        {
            float t1[4];
            #pragma unroll
            for (int j = 0; j < 4; ++j)
                t1[j] = tanhf(f0 * sw1[j * 2] + f1 * sw1[j * 2 + 1] + sb1[j]);
            float s0 = sb2[0], s1v = sb2[1];
            #pragma unroll
            for (int j = 0; j < 4; ++j) { s0 += t1[j] * sw2[j]; s1v += t1[j] * sw2[4 + j]; }
            float mx = fmaxf(s0, s1v);
            float e0 = expf(s0 - mx), e1 = expf(s1v - mx);
            float inv = 1.f / (e0 + e1);
            out[off_samp + (size_t)img * 2 + 0] = e0 * inv;
            out[off_samp + (size_t)img * 2 + 1] = e1 * inv;
        }
        {
            float e1a[8];
            #pragma unroll
            for (int j = 0; j < 8; ++j)
                e1a[j] = tanhf(f0 * ew1[j * 2] + f1 * ew1[j * 2 + 1] + eb1[j]);
            float rg = eb3[0];
            #pragma unroll
            for (int m = 0; m < 4; ++m) {
                float a = eb2[m];
                #pragma unroll
                for (int j = 0; j < 8; ++j) a += e1a[j] * ew2[m * 8 + j];
                rg += tanhf(a) * ew3[m];
            }
            out[off_reg + img] = rg;
        }
    }

    {
        float4 r;
        r.x = fct[img]           * sc[0] + shf[0];
        r.y = fct[bsz + img]     * sc[1] + shf[1];
        r.z = fct[2 * bsz + img] * sc[2] + shf[2];
        r.w = fct[3 * bsz + img] * sc[3] + shf[3];
        *(float4*)(out + (size_t)img * 4) = r;
    }
}

// ---------------------------------------------------------------------------
extern "C" void kernel_launch(void* const* d_in, const int* in_sizes, int n_in,
                              void* d_out, int out_size, void* d_ws, size_t ws_size,
                              hipStream_t stream) {
    const float* x     = (const float*)d_in[0];
    const float* c1w   = (const float*)d_in[1];
    const float* c1b   = (const float*)d_in[2];
    const float* c2w   = (const float*)d_in[3];
    const float* c2b   = (const float*)d_in[4];
    const float* fc1w  = (const float*)d_in[5];
    const float* fc1b  = (const float*)d_in[6];
    const float* fc2w  = (const float*)d_in[7];
    const float* fc2b  = (const float*)d_in[8];
    const float* bng   = (const float*)d_in[9];
    const float* bnb   = (const float*)d_in[10];
    const float* sw1   = (const float*)d_in[11];
    const float* sb1   = (const float*)d_in[12];
    const float* sw2   = (const float*)d_in[13];
    const float* sb2   = (const float*)d_in[14];
    const float* ew1   = (const float*)d_in[15];
    const float* eb1   = (const float*)d_in[16];
    const float* ew2   = (const float*)d_in[17];
    const float* eb2   = (const float*)d_in[18];
    const float* ew3   = (const float*)d_in[19];
    const float* eb3   = (const float*)d_in[20];
    const float* mem   = (const float*)d_in[21];

    const int bsz = in_sizes[0] / 784;         // 8192
    float* out = (float*)d_out;

    unsigned short* flatb = (unsigned short*)d_ws;           // bsz*800 bf16
    unsigned short* Bp    = flatb + (size_t)bsz * 800;       // 51200 bf16
    float* fct            = (float*)(Bp + 51200);            // 4*bsz
    float* partial        = fct + (size_t)bsz * 4;           // 256*8
    float* exact4g        = partial + 2048;                  // 4*bsz

    k_conv<<<bsz / 2, 256, 0, stream>>>(x, c1w, c1b, c2w, c2b,
                                        fc1w, Bp, flatb, exact4g, bsz);
    k_fc<<<bsz / 32, 128, 0, stream>>>(flatb, Bp, fc1b, fc2w, fc2b,
                                       fct, partial, bsz);
    k_bnheads<<<bsz / 256, 256, 0, stream>>>(partial, bng, bnb, fct, exact4g,
                                             sw1, sb1, sw2, sb2,
                                             ew1, eb1, ew2, eb2, ew3, eb3, mem,
                                             out, bsz);
}